// Round 6
// baseline (2891.862 us; speedup 1.0000x reference)
//
#include <hip/hip_runtime.h>
#include <cstdint>
#include <cstddef>

#define M_POS 4096
#define NCH   256
#define KTOT  9216
#define NANCH 36864
#define NSORT 65536
#define PRE   6000
#define POST  2000
#define NGRP  94
#define MROW  6016  // padded maskT row stride (u64 elements)

typedef unsigned long long u64;
typedef unsigned int u32;

__device__ __forceinline__ u32 ord_f32(float f) {
  u32 u = __float_as_uint(f);
  return (u & 0x80000000u) ? ~u : (u | 0x80000000u);
}

// ---------------- conv 3x3 as im2col GEMM: M=4096, N=256, K=9216 --------
// BM=128, BN=128, BK=16, 256 threads, 8x8 per thread (split 4+4 frags).
__global__ __launch_bounds__(256) void conv3x3(const float* __restrict__ in,
                                               const float* __restrict__ wgt,
                                               float* __restrict__ part,
                                               int kPer) {
  __shared__ __align__(16) float As[16][128];
  __shared__ __align__(16) float Bs[16][128];
  int tid = threadIdx.x;
  int bm = blockIdx.x << 7;
  int bn = blockIdx.y << 7;
  int kBeg = blockIdx.z * kPer;
  int am = tid & 127;
  int aq = (tid >> 7) << 2;
  int gm = bm + am;
  int y = gm >> 6, x = gm & 63;
  int bkk = tid >> 5;
  int bn4 = (tid & 31) << 2;
  int ty = tid >> 4, tx = tid & 15;

  float acc[8][8];
#pragma unroll
  for (int i = 0; i < 8; ++i)
#pragma unroll
    for (int j = 0; j < 8; ++j) acc[i][j] = 0.f;

  for (int k0 = kBeg; k0 < kBeg + kPer; k0 += 16) {
#pragma unroll
    for (int p = 0; p < 2; ++p) {
      int kk = aq + (p << 3);
      int k = k0 + kk;
      int tap = k >> 10;
      int c = k & 1023;
      int iy = y + tap / 3 - 1;
      int ix = x + tap % 3 - 1;
      float4 v = make_float4(0.f, 0.f, 0.f, 0.f);
      if (iy >= 0 && iy < 64 && ix >= 0 && ix < 64)
        v = *(const float4*)(in + (size_t)((((iy << 6) + ix) << 10) + c));
      As[kk + 0][am] = v.x;
      As[kk + 1][am] = v.y;
      As[kk + 2][am] = v.z;
      As[kk + 3][am] = v.w;
    }
#pragma unroll
    for (int p = 0; p < 2; ++p) {
      int kk = bkk + (p << 3);
      *(float4*)&Bs[kk][bn4] =
          *(const float4*)(wgt + (size_t)(k0 + kk) * NCH + bn + bn4);
    }
    __syncthreads();
#pragma unroll
    for (int kk = 0; kk < 16; ++kk) {
      float4 a0 = *(const float4*)&As[kk][ty << 2];
      float4 a1 = *(const float4*)&As[kk][64 + (ty << 2)];
      float4 b0 = *(const float4*)&Bs[kk][tx << 2];
      float4 b1 = *(const float4*)&Bs[kk][64 + (tx << 2)];
      float a[8] = {a0.x, a0.y, a0.z, a0.w, a1.x, a1.y, a1.z, a1.w};
      float b[8] = {b0.x, b0.y, b0.z, b0.w, b1.x, b1.y, b1.z, b1.w};
#pragma unroll
      for (int i = 0; i < 8; ++i)
#pragma unroll
        for (int j = 0; j < 8; ++j) acc[i][j] += a[i] * b[j];
    }
    __syncthreads();
  }
  size_t ob = (size_t)blockIdx.z * ((size_t)M_POS * NCH);
#pragma unroll
  for (int i = 0; i < 8; ++i) {
    int row = bm + ((i < 4) ? ((ty << 2) + i) : (64 + (ty << 2) + i - 4));
    float4 o0 = make_float4(acc[i][0], acc[i][1], acc[i][2], acc[i][3]);
    float4 o1 = make_float4(acc[i][4], acc[i][5], acc[i][6], acc[i][7]);
    *(float4*)(part + ob + (size_t)row * NCH + bn + (tx << 2)) = o0;
    *(float4*)(part + ob + (size_t)row * NCH + bn + 64 + (tx << 2)) = o1;
  }
}

__global__ __launch_bounds__(256) void reduce_bias(const float* __restrict__ part,
                                                   const float* __restrict__ bias,
                                                   float* __restrict__ outp, int ks) {
  int idx = blockIdx.x * 256 + threadIdx.x;
  float v = 0.f;
  for (int s = 0; s < ks; ++s) v += part[(size_t)s * (M_POS * NCH) + idx];
  outp[idx] = v + bias[idx & 255];
}

// ---------------- 1x1 conv heads: cls (256->18), bbox (256->36) ----------
__global__ __launch_bounds__(64) void conv1x1(const float* __restrict__ sh,
                                              const float* __restrict__ wc,
                                              const float* __restrict__ bc,
                                              const float* __restrict__ wb,
                                              const float* __restrict__ bb2,
                                              float* __restrict__ cls,
                                              float* __restrict__ bbox) {
  __shared__ float row[256];
  int pos = blockIdx.x;
  int tid = threadIdx.x;
  *(float4*)&row[tid * 4] = *(const float4*)(sh + (size_t)pos * 256 + tid * 4);
  __syncthreads();
  if (tid < 18) {
    float acc = bc[tid];
    for (int c = 0; c < 256; ++c) acc += row[c] * wc[c * 18 + tid];
    cls[(size_t)pos * 18 + tid] = acc;
  } else if (tid < 54) {
    int n = tid - 18;
    float acc = bb2[n];
    for (int c = 0; c < 256; ++c) acc += row[c] * wb[c * 36 + n];
    bbox[(size_t)pos * 36 + n] = acc;
  }
}

// ---------------- scores + box decode + clip -----------------------------
__global__ __launch_bounds__(256) void proposals_k(const float* __restrict__ cls,
                                                   const float* __restrict__ bb,
                                                   float* __restrict__ scores,
                                                   float* __restrict__ prop) {
  int idx = blockIdx.x * 256 + threadIdx.x;
  if (idx >= NANCH) return;
  int a = idx % 9;
  int pos = idx / 9;
  int x = pos & 63, y = pos >> 6;
  float s0 = cls[(size_t)pos * 18 + 2 * a];
  float s1 = cls[(size_t)pos * 18 + 2 * a + 1];
  float mx = fmaxf(s0, s1);
  float e0 = expf(s0 - mx), e1 = expf(s1 - mx);
  scores[idx] = e1 / (e0 + e1);
  const float AW[9] = {184.f, 368.f, 736.f, 128.f, 256.f, 512.f, 88.f, 176.f, 352.f};
  const float AH[9] = {96.f, 192.f, 384.f, 128.f, 256.f, 512.f, 176.f, 352.f, 704.f};
  float w = AW[a], h = AH[a];
  float cx = (float)(x * 16) + 8.0f;
  float cy = (float)(y * 16) + 8.0f;
  float dx = bb[(size_t)pos * 36 + 4 * a + 0];
  float dy = bb[(size_t)pos * 36 + 4 * a + 1];
  float dw = bb[(size_t)pos * 36 + 4 * a + 2];
  float dh = bb[(size_t)pos * 36 + 4 * a + 3];
  dw = fminf(fmaxf(dw, -4.135f), 4.135f);
  dh = fminf(fmaxf(dh, -4.135f), 4.135f);
  float pcx = dx * w + cx;
  float pcy = dy * h + cy;
  float pw = expf(dw) * w;
  float ph = expf(dh) * h;
  float x1 = pcx - 0.5f * pw, y1 = pcy - 0.5f * ph;
  float x2 = pcx + 0.5f * pw, y2 = pcy + 0.5f * ph;
  x1 = fminf(fmaxf(x1, 0.f), 1023.f);
  y1 = fminf(fmaxf(y1, 0.f), 1023.f);
  x2 = fminf(fmaxf(x2, 0.f), 1023.f);
  y2 = fminf(fmaxf(y2, 0.f), 1023.f);
  prop[(size_t)idx * 4 + 0] = x1;
  prop[(size_t)idx * 4 + 1] = y1;
  prop[(size_t)idx * 4 + 2] = x2;
  prop[(size_t)idx * 4 + 3] = y2;
}

// ---------------- composite sort keys (score desc, index asc) ------------
__global__ __launch_bounds__(256) void build_keys(const float* __restrict__ scores,
                                                  u64* __restrict__ keys) {
  int i = blockIdx.x * 256 + threadIdx.x;
  if (i >= NSORT) return;
  u64 k = 0ull;
  if (i < NANCH) {
    u32 u = ord_f32(scores[i]);
    k = ((u64)u << 32) | (u64)(0xFFFFFFFFu - (u32)i);
  }
  keys[i] = k;
}

// bitonic sort, DESCENDING. Direction: (i & k)==0 -> desc.
__global__ __launch_bounds__(1024) void sort_local(u64* keys) {
  __shared__ u64 s[2048];
  int base = blockIdx.x * 2048;
  s[threadIdx.x] = keys[base + threadIdx.x];
  s[threadIdx.x + 1024] = keys[base + threadIdx.x + 1024];
  __syncthreads();
  for (int k = 2; k <= 2048; k <<= 1) {
    for (int j = k >> 1; j >= 1; j >>= 1) {
      int t = threadIdx.x;
      int i = ((t & ~(j - 1)) << 1) | (t & (j - 1));
      int p = i | j;
      bool desc = (((base + i) & k) == 0);
      u64 a = s[i], b = s[p];
      if (desc ? (a < b) : (a > b)) { s[i] = b; s[p] = a; }
      __syncthreads();
    }
  }
  keys[base + threadIdx.x] = s[threadIdx.x];
  keys[base + threadIdx.x + 1024] = s[threadIdx.x + 1024];
}

__device__ __forceinline__ void cmpswap(u64& a, u64& b, bool desc) {
  if (desc ? (a < b) : (a > b)) { u64 t = a; a = b; b = t; }
}

__global__ __launch_bounds__(256) void sort_gstep(u64* keys, int k, int j) {
  int t = blockIdx.x * 256 + threadIdx.x;
  int i = ((t & ~(j - 1)) << 1) | (t & (j - 1));
  int p = i | j;
  bool desc = ((i & k) == 0);
  u64 a = keys[i], b = keys[p];
  if (desc ? (a < b) : (a > b)) { keys[i] = b; keys[p] = a; }
}

// two bitonic levels (j and j/2) per pass, 4 elements per thread
__global__ __launch_bounds__(256) void sort_gstep2(u64* keys, int k, int j) {
  int t = blockIdx.x * 256 + threadIdx.x; // NSORT/4 threads
  int j2 = j >> 1;
  int a = ((t & ~(j2 - 1)) << 1) | (t & (j2 - 1));
  int i0 = ((a & ~(j - 1)) << 1) | (a & (j - 1));
  int i1 = i0 | j2, i2 = i0 | j, i3 = i0 | j | j2;
  bool desc = ((i0 & k) == 0);
  u64 v0 = keys[i0], v1 = keys[i1], v2 = keys[i2], v3 = keys[i3];
  cmpswap(v0, v2, desc);
  cmpswap(v1, v3, desc);
  cmpswap(v0, v1, desc);
  cmpswap(v2, v3, desc);
  keys[i0] = v0; keys[i1] = v1; keys[i2] = v2; keys[i3] = v3;
}

__global__ __launch_bounds__(1024) void sort_lstep(u64* keys, int k) {
  __shared__ u64 s[2048];
  int base = blockIdx.x * 2048;
  s[threadIdx.x] = keys[base + threadIdx.x];
  s[threadIdx.x + 1024] = keys[base + threadIdx.x + 1024];
  __syncthreads();
  for (int j = 1024; j >= 1; j >>= 1) {
    int t = threadIdx.x;
    int i = ((t & ~(j - 1)) << 1) | (t & (j - 1));
    int p = i | j;
    bool desc = (((base + i) & k) == 0);
    u64 a = s[i], b = s[p];
    if (desc ? (a < b) : (a > b)) { s[i] = b; s[p] = a; }
    __syncthreads();
  }
  keys[base + threadIdx.x] = s[threadIdx.x];
  keys[base + threadIdx.x + 1024] = s[threadIdx.x + 1024];
}

__global__ __launch_bounds__(256) void gather_top(const u64* __restrict__ keys,
                                                  const float4* __restrict__ prop,
                                                  float4* __restrict__ topbox) {
  int i = blockIdx.x * 256 + threadIdx.x;
  if (i >= PRE) return;
  u64 kk = keys[i];
  u32 idx = 0xFFFFFFFFu - (u32)(kk & 0xFFFFFFFFull);
  topbox[i] = prop[idx];
}

// ------------- NMS suppression-mask matrix, TRANSPOSED: maskT[g][i] ------
// bit b of maskT[g*MROW + i] = (box i suppresses box g*64+b), i.e. iou>th & j>i
__global__ __launch_bounds__(64) void nms_mask(const float4* __restrict__ boxes,
                                               u64* __restrict__ maskT) {
  __shared__ float4 cb[64];
  int ci = blockIdx.x, ri = blockIdx.y;
  int t = threadIdx.x;
  int col = (ci << 6) + t;
  cb[t] = (col < PRE) ? boxes[col] : make_float4(0.f, 0.f, 0.f, 0.f);
  __syncthreads();
  int r = (ri << 6) + t;
  if (r >= PRE) return;
  float4 rb = boxes[r];
  float ra = (rb.z - rb.x + 1.f) * (rb.w - rb.y + 1.f);
  u64 bits = 0ull;
  for (int cc = 0; cc < 64; ++cc) {
    int j = (ci << 6) + cc;
    if (j > r && j < PRE) {
      float4 b = cb[cc];
      float ba = (b.z - b.x + 1.f) * (b.w - b.y + 1.f);
      float xx1 = fmaxf(rb.x, b.x), yy1 = fmaxf(rb.y, b.y);
      float xx2 = fminf(rb.z, b.z), yy2 = fminf(rb.w, b.w);
      float iw = fmaxf(xx2 - xx1 + 1.f, 0.f);
      float ih = fmaxf(yy2 - yy1 + 1.f, 0.f);
      float inter = iw * ih;
      float iou = inter / (ra + ba - inter);
      if (iou > 0.7f) bits |= (1ull << cc);
    }
  }
  maskT[(size_t)ci * MROW + r] = bits;
}

// ------------- greedy NMS scan v3: software-pipelined push, no atomics ----
// Wave 0: per-group serial scan with intra masks hoisted into m[64] regs.
// Waves 1..15: own future groups (gp = wv-1 + 15i), hold ext accumulators in
// registers, apply one predicated OR per round; 6-shfl reduce only at handoff.
// All global loads issued one round ahead (latency spans 2 barriers + scan).
__global__ __launch_bounds__(1024) void nms_scan(const u64* __restrict__ maskT,
                                                 u64* __restrict__ keepw) {
  __shared__ u64 keepS;
  __shared__ u64 extS;
  const int tid = threadIdx.x;
  const int lane = tid & 63, wv = tid >> 6;
  const int gpB = wv - 1;

  u64 acc[7], v[7];
#pragma unroll
  for (int i = 0; i < 7; ++i) { acc[i] = 0ull; v[i] = 0ull; }

  // prologue: round-0 loads (columns 0..63) for owned gp >= 1
  if (wv > 0) {
#pragma unroll
    for (int i = 0; i < 7; ++i) {
      int gp = gpB + 15 * i;
      if (gp >= 1 && gp < NGRP) v[i] = maskT[(size_t)gp * MROW + lane];
    }
  }
  u64 x = 0ull;
  u64 m[64];
  if (wv == 0) x = maskT[lane];  // intra row of group 0

  for (int g = 0; g < NGRP; ++g) {
    if (wv == 0) {
      // hoist intra masks out of the dependent chain (64 independent shfls)
#pragma unroll
      for (int t = 0; t < 64; ++t) m[t] = __shfl(x, t, 64);
      u64 cur = (g == 0) ? 0ull : extS;
      u64 keep = 0ull;
#pragma unroll
      for (int t = 0; t < 64; ++t) {
        if (!((cur >> t) & 1ull)) { keep |= (1ull << t); cur |= m[t]; }
      }
      if (g == NGRP - 1) keep &= (1ull << 48) - 1ull; // 6000 = 93*64+48
      if (lane == 0) { keepS = keep; keepw[g] = keep; }
      // prefetch intra row for g+1 (consumed next iteration)
      if (g + 1 < NGRP) {
        int ii = ((g + 1) << 6) + lane;
        x = (ii < PRE) ? maskT[(size_t)(g + 1) * MROW + ii] : 0ull;
      }
    }
    __syncthreads();  // keepS visible; extS (for g) consumed
    if (wv > 0) {
      u64 kb = keepS;
      u64 sel = ((kb >> lane) & 1ull) ? ~0ull : 0ull;
      u64 e = 0ull;
      bool own = false;
#pragma unroll
      for (int i = 0; i < 7; ++i) {
        int gp = gpB + 15 * i;
        if (gp < NGRP && gp > g) {
          acc[i] |= (v[i] & sel);
          if (gp == g + 1) { e = acc[i]; own = true; }
        }
      }
      if (own) {  // wave-uniform: exactly one wave owns g+1
#pragma unroll
        for (int s = 1; s < 64; s <<= 1) e |= __shfl_xor(e, s, 64);
        if (lane == 0) extS = e;
      }
      // issue loads for round g+1 (column block 64*(g+1)), gp > g+1
      int col = ((g + 1) << 6) + lane;
#pragma unroll
      for (int i = 0; i < 7; ++i) {
        int gp = gpB + 15 * i;
        if (gp < NGRP && gp > g + 1) v[i] = maskT[(size_t)gp * MROW + col];
      }
    }
    __syncthreads();  // extS (for g+1) visible to wave 0
  }
}

// -------- sel = argsort(keep?idx:6000+idx)[:2000]; gather roi boxes ------
__global__ __launch_bounds__(1024) void select_rois(const u64* __restrict__ keepw,
                                                    const float4* __restrict__ topbox,
                                                    float4* __restrict__ roibox) {
  __shared__ u32 wscan[NGRP + 1];
  __shared__ u32 wc[NGRP];
  int tid = threadIdx.x;
  if (tid < NGRP) wc[tid] = (u32)__popcll(keepw[tid]);
  __syncthreads();
  if (tid == 0) {
    u32 r = 0;
    for (int g = 0; g < NGRP; ++g) { wscan[g] = r; r += wc[g]; }
    wscan[NGRP] = r;
  }
  __syncthreads();
  u32 ktot = wscan[NGRP];
  for (int i = tid; i < PRE; i += 1024) {
    int g = i >> 6, t = i & 63;
    u64 w = keepw[g];
    bool kept = (w >> t) & 1ull;
    u32 pk = wscan[g] + (u32)__popcll(w & ((1ull << t) - 1ull));
    u32 pos = kept ? pk : (ktot + (u32)i - pk);
    if (pos < POST) roibox[pos] = topbox[i];
  }
}

// ---------------- ROI sampling: IoU vs gt, fg/bg stable top-k ------------
__device__ void bitonic2048_desc(u64* s) {
  int tid = threadIdx.x;
  for (int k = 2; k <= 2048; k <<= 1) {
    for (int j = k >> 1; j >= 1; j >>= 1) {
      int i = ((tid & ~(j - 1)) << 1) | (tid & (j - 1));
      int p = i | j;
      bool desc = ((i & k) == 0);
      u64 a = s[i], b = s[p];
      if (desc ? (a < b) : (a > b)) { s[i] = b; s[p] = a; }
      __syncthreads();
    }
  }
}

__global__ __launch_bounds__(1024) void roi_sample(const float4* __restrict__ roibox,
                                                   const float* __restrict__ gt,
                                                   float* __restrict__ out) {
  __shared__ float mov[POST];
  __shared__ u64 sk[2048];
  __shared__ float gtb[20][4];
  __shared__ int fgsel[32];
  __shared__ int bgsel[96];
  int tid = threadIdx.x;
  if (tid < 20) {
    gtb[tid][0] = gt[tid * 5 + 0];
    gtb[tid][1] = gt[tid * 5 + 1];
    gtb[tid][2] = gt[tid * 5 + 2];
    gtb[tid][3] = gt[tid * 5 + 3];
  }
  __syncthreads();
  for (int i = tid; i < POST; i += 1024) {
    float4 b = roibox[i];
    float aa = (b.z - b.x + 1.f) * (b.w - b.y + 1.f);
    float m = -3.402823466e38f;
    for (int t = 0; t < 20; ++t) {
      float gx1 = gtb[t][0], gy1 = gtb[t][1], gx2 = gtb[t][2], gy2 = gtb[t][3];
      float ga = (gx2 - gx1 + 1.f) * (gy2 - gy1 + 1.f);
      float xx1 = fmaxf(b.x, gx1), yy1 = fmaxf(b.y, gy1);
      float xx2 = fminf(b.z, gx2), yy2 = fminf(b.w, gy2);
      float iw = fmaxf(xx2 - xx1 + 1.f, 0.f);
      float ih = fmaxf(yy2 - yy1 + 1.f, 0.f);
      float inter = iw * ih;
      float iou = inter / (aa + ga - inter);
      m = fmaxf(m, iou);
    }
    mov[i] = m;
  }
  __syncthreads();
  for (int i = tid; i < 2048; i += 1024) {
    float key;
    if (i < POST) { float v = mov[i]; key = (v >= 0.5f) ? v : -1.0f; }
    else key = -2.0f;
    sk[i] = ((u64)ord_f32(key) << 32) | (u64)(2047u - (u32)i);
  }
  __syncthreads();
  bitonic2048_desc(sk);
  if (tid < 32) fgsel[tid] = (int)(2047u - (u32)(sk[tid] & 0xFFFFFFFFull));
  __syncthreads();
  for (int i = tid; i < 2048; i += 1024) {
    float key;
    if (i < POST) {
      float v = mov[i];
      key = (v < 0.5f && v >= 0.1f) ? v : -1.0f;
    } else key = -2.0f;
    sk[i] = ((u64)ord_f32(key) << 32) | (u64)(2047u - (u32)i);
  }
  __syncthreads();
  bitonic2048_desc(sk);
  if (tid < 96) bgsel[tid] = (int)(2047u - (u32)(sk[tid] & 0xFFFFFFFFull));
  __syncthreads();
  if (tid < 128) {
    int idx = (tid < 32) ? fgsel[tid] : bgsel[tid - 32];
    float4 b = roibox[idx];
    out[tid * 5 + 0] = 0.f;
    out[tid * 5 + 1] = b.x;
    out[tid * 5 + 2] = b.y;
    out[tid * 5 + 3] = b.z;
    out[tid * 5 + 4] = b.w;
  }
}

// ---------------- host launch ----------------
extern "C" void kernel_launch(void* const* d_in, const int* in_sizes, int n_in,
                              void* d_out, int out_size, void* d_ws, size_t ws_size,
                              hipStream_t stream) {
  const float* in   = (const float*)d_in[0];
  const float* wsh  = (const float*)d_in[1];
  const float* bsh  = (const float*)d_in[2];
  const float* wcls = (const float*)d_in[3];
  const float* bcls = (const float*)d_in[4];
  const float* wbb  = (const float*)d_in[5];
  const float* bbb  = (const float*)d_in[6];
  const float* gt   = (const float*)d_in[7];

  char* w = (char*)d_ws;
  const size_t OFF_SHARED = 0;          // 4,194,304 conv out (also keys later)
  const size_t OFF_CLS    = 4194304;    // 294,912
  const size_t OFF_BBOX   = 4489216;    // 589,824
  const size_t OFF_SCORES = 5079040;    // 147,456
  const size_t OFF_PROP   = 5226496;    // 589,824 -> 5,816,320
  const size_t OFF_KEYS   = 0;          // reuse (dead after conv1x1)
  const size_t OFF_TOPBOX = 524288;     // 96,000 -> 620,288
  const size_t OFF_MASK   = 620288;     // 94*6016*8 = 4,524,032 -> 5,144,320
  const size_t OFF_KEEPW  = 5144320;    // 752
  const size_t OFF_ROIBOX = 5145088;    // 32,000 -> 5,177,088
  const size_t OFF_PART   = 5816320;    // KS * 4MB split-K partials

  float* sharedb = (float*)(w + OFF_SHARED);
  float* cls     = (float*)(w + OFF_CLS);
  float* bbox    = (float*)(w + OFF_BBOX);
  float* scores  = (float*)(w + OFF_SCORES);
  float* prop    = (float*)(w + OFF_PROP);
  u64*   keys    = (u64*)(w + OFF_KEYS);
  float4* topbox = (float4*)(w + OFF_TOPBOX);
  u64*   maskT   = (u64*)(w + OFF_MASK);
  u64*   keepw   = (u64*)(w + OFF_KEEPW);
  float4* roibox = (float4*)(w + OFF_ROIBOX);
  float* out     = (float*)d_out;

  const size_t SLICE = (size_t)M_POS * NCH * 4;
  int KS = 1;
  if (ws_size >= OFF_PART + 8 * SLICE) KS = 8;
  else if (ws_size >= OFF_PART + 4 * SLICE) KS = 4;
  else if (ws_size >= OFF_PART + 2 * SLICE) KS = 2;
  float* part = (KS > 1) ? (float*)(w + OFF_PART) : sharedb;

  conv3x3<<<dim3(32, 2, KS), 256, 0, stream>>>(in, wsh, part, KTOT / KS);
  reduce_bias<<<4096, 256, 0, stream>>>(part, bsh, sharedb, KS);
  conv1x1<<<4096, 64, 0, stream>>>(sharedb, wcls, bcls, wbb, bbb, cls, bbox);
  proposals_k<<<144, 256, 0, stream>>>(cls, bbox, scores, prop);
  build_keys<<<256, 256, 0, stream>>>(scores, keys);
  sort_local<<<32, 1024, 0, stream>>>(keys);
  for (int k = 4096; k <= NSORT; k <<= 1) {
    int j = k >> 1;
    while (j >= 4096) {
      sort_gstep2<<<64, 256, 0, stream>>>(keys, k, j);
      j >>= 2;
    }
    if (j == 2048) {
      sort_gstep<<<128, 256, 0, stream>>>(keys, k, j);
      j >>= 1;
    }
    sort_lstep<<<32, 1024, 0, stream>>>(keys, k);
  }
  gather_top<<<24, 256, 0, stream>>>(keys, (const float4*)prop, topbox);
  nms_mask<<<dim3(NGRP, NGRP), 64, 0, stream>>>(topbox, maskT);
  nms_scan<<<1, 1024, 0, stream>>>(maskT, keepw);
  select_rois<<<1, 1024, 0, stream>>>(keepw, topbox, roibox);
  roi_sample<<<1, 1024, 0, stream>>>(roibox, gt, out);
}

// Round 7
// 2882.994 us; speedup vs baseline: 1.0031x; 1.0031x over previous
//
#include <hip/hip_runtime.h>
#include <cstdint>
#include <cstddef>

#define M_POS 4096
#define NCH   256
#define KTOT  9216
#define NANCH 36864
#define NSORT 65536
#define PRE   6000
#define POST  2000
#define NGRP  94
#define MROW  6016  // padded maskT row stride (u64 elements)

typedef unsigned long long u64;
typedef unsigned int u32;

__device__ __forceinline__ u32 ord_f32(float f) {
  u32 u = __float_as_uint(f);
  return (u & 0x80000000u) ? ~u : (u | 0x80000000u);
}

// ---------------- conv 3x3 as im2col GEMM: M=4096, N=256, K=9216 --------
// BM=128, BN=128, BK=16, 256 threads, 8x8 per thread (split 4+4 frags).
__global__ __launch_bounds__(256) void conv3x3(const float* __restrict__ in,
                                               const float* __restrict__ wgt,
                                               float* __restrict__ part,
                                               int kPer) {
  __shared__ __align__(16) float As[16][128];
  __shared__ __align__(16) float Bs[16][128];
  int tid = threadIdx.x;
  int bm = blockIdx.x << 7;
  int bn = blockIdx.y << 7;
  int kBeg = blockIdx.z * kPer;
  int am = tid & 127;
  int aq = (tid >> 7) << 2;
  int gm = bm + am;
  int y = gm >> 6, x = gm & 63;
  int bkk = tid >> 5;
  int bn4 = (tid & 31) << 2;
  int ty = tid >> 4, tx = tid & 15;

  float acc[8][8];
#pragma unroll
  for (int i = 0; i < 8; ++i)
#pragma unroll
    for (int j = 0; j < 8; ++j) acc[i][j] = 0.f;

  for (int k0 = kBeg; k0 < kBeg + kPer; k0 += 16) {
#pragma unroll
    for (int p = 0; p < 2; ++p) {
      int kk = aq + (p << 3);
      int k = k0 + kk;
      int tap = k >> 10;
      int c = k & 1023;
      int iy = y + tap / 3 - 1;
      int ix = x + tap % 3 - 1;
      float4 v = make_float4(0.f, 0.f, 0.f, 0.f);
      if (iy >= 0 && iy < 64 && ix >= 0 && ix < 64)
        v = *(const float4*)(in + (size_t)((((iy << 6) + ix) << 10) + c));
      As[kk + 0][am] = v.x;
      As[kk + 1][am] = v.y;
      As[kk + 2][am] = v.z;
      As[kk + 3][am] = v.w;
    }
#pragma unroll
    for (int p = 0; p < 2; ++p) {
      int kk = bkk + (p << 3);
      *(float4*)&Bs[kk][bn4] =
          *(const float4*)(wgt + (size_t)(k0 + kk) * NCH + bn + bn4);
    }
    __syncthreads();
#pragma unroll
    for (int kk = 0; kk < 16; ++kk) {
      float4 a0 = *(const float4*)&As[kk][ty << 2];
      float4 a1 = *(const float4*)&As[kk][64 + (ty << 2)];
      float4 b0 = *(const float4*)&Bs[kk][tx << 2];
      float4 b1 = *(const float4*)&Bs[kk][64 + (tx << 2)];
      float a[8] = {a0.x, a0.y, a0.z, a0.w, a1.x, a1.y, a1.z, a1.w};
      float b[8] = {b0.x, b0.y, b0.z, b0.w, b1.x, b1.y, b1.z, b1.w};
#pragma unroll
      for (int i = 0; i < 8; ++i)
#pragma unroll
        for (int j = 0; j < 8; ++j) acc[i][j] += a[i] * b[j];
    }
    __syncthreads();
  }
  size_t ob = (size_t)blockIdx.z * ((size_t)M_POS * NCH);
#pragma unroll
  for (int i = 0; i < 8; ++i) {
    int row = bm + ((i < 4) ? ((ty << 2) + i) : (64 + (ty << 2) + i - 4));
    float4 o0 = make_float4(acc[i][0], acc[i][1], acc[i][2], acc[i][3]);
    float4 o1 = make_float4(acc[i][4], acc[i][5], acc[i][6], acc[i][7]);
    *(float4*)(part + ob + (size_t)row * NCH + bn + (tx << 2)) = o0;
    *(float4*)(part + ob + (size_t)row * NCH + bn + 64 + (tx << 2)) = o1;
  }
}

__global__ __launch_bounds__(256) void reduce_bias(const float* __restrict__ part,
                                                   const float* __restrict__ bias,
                                                   float* __restrict__ outp, int ks) {
  int idx = blockIdx.x * 256 + threadIdx.x;
  float v = 0.f;
  for (int s = 0; s < ks; ++s) v += part[(size_t)s * (M_POS * NCH) + idx];
  outp[idx] = v + bias[idx & 255];
}

// ---------------- 1x1 conv heads: cls (256->18), bbox (256->36) ----------
__global__ __launch_bounds__(64) void conv1x1(const float* __restrict__ sh,
                                              const float* __restrict__ wc,
                                              const float* __restrict__ bc,
                                              const float* __restrict__ wb,
                                              const float* __restrict__ bb2,
                                              float* __restrict__ cls,
                                              float* __restrict__ bbox) {
  __shared__ float row[256];
  int pos = blockIdx.x;
  int tid = threadIdx.x;
  *(float4*)&row[tid * 4] = *(const float4*)(sh + (size_t)pos * 256 + tid * 4);
  __syncthreads();
  if (tid < 18) {
    float acc = bc[tid];
    for (int c = 0; c < 256; ++c) acc += row[c] * wc[c * 18 + tid];
    cls[(size_t)pos * 18 + tid] = acc;
  } else if (tid < 54) {
    int n = tid - 18;
    float acc = bb2[n];
    for (int c = 0; c < 256; ++c) acc += row[c] * wb[c * 36 + n];
    bbox[(size_t)pos * 36 + n] = acc;
  }
}

// ---------------- scores + box decode + clip -----------------------------
__global__ __launch_bounds__(256) void proposals_k(const float* __restrict__ cls,
                                                   const float* __restrict__ bb,
                                                   float* __restrict__ scores,
                                                   float* __restrict__ prop) {
  int idx = blockIdx.x * 256 + threadIdx.x;
  if (idx >= NANCH) return;
  int a = idx % 9;
  int pos = idx / 9;
  int x = pos & 63, y = pos >> 6;
  float s0 = cls[(size_t)pos * 18 + 2 * a];
  float s1 = cls[(size_t)pos * 18 + 2 * a + 1];
  float mx = fmaxf(s0, s1);
  float e0 = expf(s0 - mx), e1 = expf(s1 - mx);
  scores[idx] = e1 / (e0 + e1);
  const float AW[9] = {184.f, 368.f, 736.f, 128.f, 256.f, 512.f, 88.f, 176.f, 352.f};
  const float AH[9] = {96.f, 192.f, 384.f, 128.f, 256.f, 512.f, 176.f, 352.f, 704.f};
  float w = AW[a], h = AH[a];
  float cx = (float)(x * 16) + 8.0f;
  float cy = (float)(y * 16) + 8.0f;
  float dx = bb[(size_t)pos * 36 + 4 * a + 0];
  float dy = bb[(size_t)pos * 36 + 4 * a + 1];
  float dw = bb[(size_t)pos * 36 + 4 * a + 2];
  float dh = bb[(size_t)pos * 36 + 4 * a + 3];
  dw = fminf(fmaxf(dw, -4.135f), 4.135f);
  dh = fminf(fmaxf(dh, -4.135f), 4.135f);
  float pcx = dx * w + cx;
  float pcy = dy * h + cy;
  float pw = expf(dw) * w;
  float ph = expf(dh) * h;
  float x1 = pcx - 0.5f * pw, y1 = pcy - 0.5f * ph;
  float x2 = pcx + 0.5f * pw, y2 = pcy + 0.5f * ph;
  x1 = fminf(fmaxf(x1, 0.f), 1023.f);
  y1 = fminf(fmaxf(y1, 0.f), 1023.f);
  x2 = fminf(fmaxf(x2, 0.f), 1023.f);
  y2 = fminf(fmaxf(y2, 0.f), 1023.f);
  prop[(size_t)idx * 4 + 0] = x1;
  prop[(size_t)idx * 4 + 1] = y1;
  prop[(size_t)idx * 4 + 2] = x2;
  prop[(size_t)idx * 4 + 3] = y2;
}

// ---------------- composite sort keys (score desc, index asc) ------------
__global__ __launch_bounds__(256) void build_keys(const float* __restrict__ scores,
                                                  u64* __restrict__ keys) {
  int i = blockIdx.x * 256 + threadIdx.x;
  if (i >= NSORT) return;
  u64 k = 0ull;
  if (i < NANCH) {
    u32 u = ord_f32(scores[i]);
    k = ((u64)u << 32) | (u64)(0xFFFFFFFFu - (u32)i);
  }
  keys[i] = k;
}

// bitonic sort, DESCENDING. Direction: (i & k)==0 -> desc.
__global__ __launch_bounds__(1024) void sort_local(u64* keys) {
  __shared__ u64 s[2048];
  int base = blockIdx.x * 2048;
  s[threadIdx.x] = keys[base + threadIdx.x];
  s[threadIdx.x + 1024] = keys[base + threadIdx.x + 1024];
  __syncthreads();
  for (int k = 2; k <= 2048; k <<= 1) {
    for (int j = k >> 1; j >= 1; j >>= 1) {
      int t = threadIdx.x;
      int i = ((t & ~(j - 1)) << 1) | (t & (j - 1));
      int p = i | j;
      bool desc = (((base + i) & k) == 0);
      u64 a = s[i], b = s[p];
      if (desc ? (a < b) : (a > b)) { s[i] = b; s[p] = a; }
      __syncthreads();
    }
  }
  keys[base + threadIdx.x] = s[threadIdx.x];
  keys[base + threadIdx.x + 1024] = s[threadIdx.x + 1024];
}

__device__ __forceinline__ void cmpswap(u64& a, u64& b, bool desc) {
  if (desc ? (a < b) : (a > b)) { u64 t = a; a = b; b = t; }
}

__global__ __launch_bounds__(256) void sort_gstep(u64* keys, int k, int j) {
  int t = blockIdx.x * 256 + threadIdx.x;
  int i = ((t & ~(j - 1)) << 1) | (t & (j - 1));
  int p = i | j;
  bool desc = ((i & k) == 0);
  u64 a = keys[i], b = keys[p];
  if (desc ? (a < b) : (a > b)) { keys[i] = b; keys[p] = a; }
}

// two bitonic levels (j and j/2) per pass, 4 elements per thread
__global__ __launch_bounds__(256) void sort_gstep2(u64* keys, int k, int j) {
  int t = blockIdx.x * 256 + threadIdx.x; // NSORT/4 threads
  int j2 = j >> 1;
  int a = ((t & ~(j2 - 1)) << 1) | (t & (j2 - 1));
  int i0 = ((a & ~(j - 1)) << 1) | (a & (j - 1));
  int i1 = i0 | j2, i2 = i0 | j, i3 = i0 | j | j2;
  bool desc = ((i0 & k) == 0);
  u64 v0 = keys[i0], v1 = keys[i1], v2 = keys[i2], v3 = keys[i3];
  cmpswap(v0, v2, desc);
  cmpswap(v1, v3, desc);
  cmpswap(v0, v1, desc);
  cmpswap(v2, v3, desc);
  keys[i0] = v0; keys[i1] = v1; keys[i2] = v2; keys[i3] = v3;
}

__global__ __launch_bounds__(1024) void sort_lstep(u64* keys, int k) {
  __shared__ u64 s[2048];
  int base = blockIdx.x * 2048;
  s[threadIdx.x] = keys[base + threadIdx.x];
  s[threadIdx.x + 1024] = keys[base + threadIdx.x + 1024];
  __syncthreads();
  for (int j = 1024; j >= 1; j >>= 1) {
    int t = threadIdx.x;
    int i = ((t & ~(j - 1)) << 1) | (t & (j - 1));
    int p = i | j;
    bool desc = (((base + i) & k) == 0);
    u64 a = s[i], b = s[p];
    if (desc ? (a < b) : (a > b)) { s[i] = b; s[p] = a; }
    __syncthreads();
  }
  keys[base + threadIdx.x] = s[threadIdx.x];
  keys[base + threadIdx.x + 1024] = s[threadIdx.x + 1024];
}

__global__ __launch_bounds__(256) void gather_top(const u64* __restrict__ keys,
                                                  const float4* __restrict__ prop,
                                                  float4* __restrict__ topbox) {
  int i = blockIdx.x * 256 + threadIdx.x;
  if (i >= PRE) return;
  u64 kk = keys[i];
  u32 idx = 0xFFFFFFFFu - (u32)(kk & 0xFFFFFFFFull);
  topbox[i] = prop[idx];
}

// ------------- NMS suppression-mask matrix, TRANSPOSED: maskT[g][i] ------
// bit b of maskT[g*MROW + i] = (box i suppresses box g*64+b), i.e. iou>th & j>i
__global__ __launch_bounds__(64) void nms_mask(const float4* __restrict__ boxes,
                                               u64* __restrict__ maskT) {
  __shared__ float4 cb[64];
  int ci = blockIdx.x, ri = blockIdx.y;
  int t = threadIdx.x;
  int col = (ci << 6) + t;
  cb[t] = (col < PRE) ? boxes[col] : make_float4(0.f, 0.f, 0.f, 0.f);
  __syncthreads();
  int r = (ri << 6) + t;
  if (r >= PRE) return;
  float4 rb = boxes[r];
  float ra = (rb.z - rb.x + 1.f) * (rb.w - rb.y + 1.f);
  u64 bits = 0ull;
  for (int cc = 0; cc < 64; ++cc) {
    int j = (ci << 6) + cc;
    if (j > r && j < PRE) {
      float4 b = cb[cc];
      float ba = (b.z - b.x + 1.f) * (b.w - b.y + 1.f);
      float xx1 = fmaxf(rb.x, b.x), yy1 = fmaxf(rb.y, b.y);
      float xx2 = fminf(rb.z, b.z), yy2 = fminf(rb.w, b.w);
      float iw = fmaxf(xx2 - xx1 + 1.f, 0.f);
      float ih = fmaxf(yy2 - yy1 + 1.f, 0.f);
      float inter = iw * ih;
      float iou = inter / (ra + ba - inter);
      if (iou > 0.7f) bits |= (1ull << cc);
    }
  }
  maskT[(size_t)ci * MROW + r] = bits;
}

// ------------- greedy NMS scan v3: software-pipelined push, no atomics ----
// Wave 0: per-group serial scan with intra masks hoisted into m[64] regs.
// Waves 1..15: own future groups (gp = wv-1 + 15i), hold ext accumulators in
// registers, apply one predicated OR per round; 6-shfl reduce only at handoff.
// All global loads issued one round ahead (latency spans 2 barriers + scan).
__global__ __launch_bounds__(1024) void nms_scan(const u64* __restrict__ maskT,
                                                 u64* __restrict__ keepw) {
  __shared__ u64 keepS;
  __shared__ u64 extS;
  const int tid = threadIdx.x;
  const int lane = tid & 63, wv = tid >> 6;
  const int gpB = wv - 1;

  u64 acc[7], v[7];
#pragma unroll
  for (int i = 0; i < 7; ++i) { acc[i] = 0ull; v[i] = 0ull; }

  // prologue: round-0 loads (columns 0..63) for owned gp >= 1
  if (wv > 0) {
#pragma unroll
    for (int i = 0; i < 7; ++i) {
      int gp = gpB + 15 * i;
      if (gp >= 1 && gp < NGRP) v[i] = maskT[(size_t)gp * MROW + lane];
    }
  }
  u64 x = 0ull;
  u64 m[64];
  if (wv == 0) x = maskT[lane];  // intra row of group 0

  for (int g = 0; g < NGRP; ++g) {
    if (wv == 0) {
      // hoist intra masks out of the dependent chain (64 independent shfls)
#pragma unroll
      for (int t = 0; t < 64; ++t) m[t] = __shfl(x, t, 64);
      u64 cur = (g == 0) ? 0ull : extS;
      u64 keep = 0ull;
#pragma unroll
      for (int t = 0; t < 64; ++t) {
        if (!((cur >> t) & 1ull)) { keep |= (1ull << t); cur |= m[t]; }
      }
      if (g == NGRP - 1) keep &= (1ull << 48) - 1ull; // 6000 = 93*64+48
      if (lane == 0) { keepS = keep; keepw[g] = keep; }
      // prefetch intra row for g+1 (consumed next iteration)
      if (g + 1 < NGRP) {
        int ii = ((g + 1) << 6) + lane;
        x = (ii < PRE) ? maskT[(size_t)(g + 1) * MROW + ii] : 0ull;
      }
    }
    __syncthreads();  // keepS visible; extS (for g) consumed
    if (wv > 0) {
      u64 kb = keepS;
      u64 sel = ((kb >> lane) & 1ull) ? ~0ull : 0ull;
      u64 e = 0ull;
      bool own = false;
#pragma unroll
      for (int i = 0; i < 7; ++i) {
        int gp = gpB + 15 * i;
        if (gp < NGRP && gp > g) {
          acc[i] |= (v[i] & sel);
          if (gp == g + 1) { e = acc[i]; own = true; }
        }
      }
      if (own) {  // wave-uniform: exactly one wave owns g+1
#pragma unroll
        for (int s = 1; s < 64; s <<= 1) e |= __shfl_xor(e, s, 64);
        if (lane == 0) extS = e;
      }
      // issue loads for round g+1 (column block 64*(g+1)), gp > g+1
      int col = ((g + 1) << 6) + lane;
#pragma unroll
      for (int i = 0; i < 7; ++i) {
        int gp = gpB + 15 * i;
        if (gp < NGRP && gp > g + 1) v[i] = maskT[(size_t)gp * MROW + col];
      }
    }
    __syncthreads();  // extS (for g+1) visible to wave 0
  }
}

// -------- sel = argsort(keep?idx:6000+idx)[:2000]; gather roi boxes ------
__global__ __launch_bounds__(1024) void select_rois(const u64* __restrict__ keepw,
                                                    const float4* __restrict__ topbox,
                                                    float4* __restrict__ roibox) {
  __shared__ u32 wscan[NGRP + 1];
  __shared__ u32 wc[NGRP];
  int tid = threadIdx.x;
  if (tid < NGRP) wc[tid] = (u32)__popcll(keepw[tid]);
  __syncthreads();
  if (tid == 0) {
    u32 r = 0;
    for (int g = 0; g < NGRP; ++g) { wscan[g] = r; r += wc[g]; }
    wscan[NGRP] = r;
  }
  __syncthreads();
  u32 ktot = wscan[NGRP];
  for (int i = tid; i < PRE; i += 1024) {
    int g = i >> 6, t = i & 63;
    u64 w = keepw[g];
    bool kept = (w >> t) & 1ull;
    u32 pk = wscan[g] + (u32)__popcll(w & ((1ull << t) - 1ull));
    u32 pos = kept ? pk : (ktot + (u32)i - pk);
    if (pos < POST) roibox[pos] = topbox[i];
  }
}

// ---------------- ROI sampling: IoU vs gt, fg/bg stable top-k ------------
__device__ void bitonic2048_desc(u64* s) {
  int tid = threadIdx.x;
  for (int k = 2; k <= 2048; k <<= 1) {
    for (int j = k >> 1; j >= 1; j >>= 1) {
      int i = ((tid & ~(j - 1)) << 1) | (tid & (j - 1));
      int p = i | j;
      bool desc = ((i & k) == 0);
      u64 a = s[i], b = s[p];
      if (desc ? (a < b) : (a > b)) { s[i] = b; s[p] = a; }
      __syncthreads();
    }
  }
}

__global__ __launch_bounds__(1024) void roi_sample(const float4* __restrict__ roibox,
                                                   const float* __restrict__ gt,
                                                   float* __restrict__ out) {
  __shared__ float mov[POST];
  __shared__ u64 sk[2048];
  __shared__ float gtb[20][4];
  __shared__ int fgsel[32];
  __shared__ int bgsel[96];
  int tid = threadIdx.x;
  if (tid < 20) {
    gtb[tid][0] = gt[tid * 5 + 0];
    gtb[tid][1] = gt[tid * 5 + 1];
    gtb[tid][2] = gt[tid * 5 + 2];
    gtb[tid][3] = gt[tid * 5 + 3];
  }
  __syncthreads();
  for (int i = tid; i < POST; i += 1024) {
    float4 b = roibox[i];
    float aa = (b.z - b.x + 1.f) * (b.w - b.y + 1.f);
    float m = -3.402823466e38f;
    for (int t = 0; t < 20; ++t) {
      float gx1 = gtb[t][0], gy1 = gtb[t][1], gx2 = gtb[t][2], gy2 = gtb[t][3];
      float ga = (gx2 - gx1 + 1.f) * (gy2 - gy1 + 1.f);
      float xx1 = fmaxf(b.x, gx1), yy1 = fmaxf(b.y, gy1);
      float xx2 = fminf(b.z, gx2), yy2 = fminf(b.w, gy2);
      float iw = fmaxf(xx2 - xx1 + 1.f, 0.f);
      float ih = fmaxf(yy2 - yy1 + 1.f, 0.f);
      float inter = iw * ih;
      float iou = inter / (aa + ga - inter);
      m = fmaxf(m, iou);
    }
    mov[i] = m;
  }
  __syncthreads();
  for (int i = tid; i < 2048; i += 1024) {
    float key;
    if (i < POST) { float v = mov[i]; key = (v >= 0.5f) ? v : -1.0f; }
    else key = -2.0f;
    sk[i] = ((u64)ord_f32(key) << 32) | (u64)(2047u - (u32)i);
  }
  __syncthreads();
  bitonic2048_desc(sk);
  if (tid < 32) fgsel[tid] = (int)(2047u - (u32)(sk[tid] & 0xFFFFFFFFull));
  __syncthreads();
  for (int i = tid; i < 2048; i += 1024) {
    float key;
    if (i < POST) {
      float v = mov[i];
      key = (v < 0.5f && v >= 0.1f) ? v : -1.0f;
    } else key = -2.0f;
    sk[i] = ((u64)ord_f32(key) << 32) | (u64)(2047u - (u32)i);
  }
  __syncthreads();
  bitonic2048_desc(sk);
  if (tid < 96) bgsel[tid] = (int)(2047u - (u32)(sk[tid] & 0xFFFFFFFFull));
  __syncthreads();
  if (tid < 128) {
    int idx = (tid < 32) ? fgsel[tid] : bgsel[tid - 32];
    float4 b = roibox[idx];
    out[tid * 5 + 0] = 0.f;
    out[tid * 5 + 1] = b.x;
    out[tid * 5 + 2] = b.y;
    out[tid * 5 + 3] = b.z;
    out[tid * 5 + 4] = b.w;
  }
}

// ---------------- host launch ----------------
extern "C" void kernel_launch(void* const* d_in, const int* in_sizes, int n_in,
                              void* d_out, int out_size, void* d_ws, size_t ws_size,
                              hipStream_t stream) {
  const float* in   = (const float*)d_in[0];
  const float* wsh  = (const float*)d_in[1];
  const float* bsh  = (const float*)d_in[2];
  const float* wcls = (const float*)d_in[3];
  const float* bcls = (const float*)d_in[4];
  const float* wbb  = (const float*)d_in[5];
  const float* bbb  = (const float*)d_in[6];
  const float* gt   = (const float*)d_in[7];

  char* w = (char*)d_ws;
  const size_t OFF_SHARED = 0;          // 4,194,304 conv out (also keys later)
  const size_t OFF_CLS    = 4194304;    // 294,912
  const size_t OFF_BBOX   = 4489216;    // 589,824
  const size_t OFF_SCORES = 5079040;    // 147,456
  const size_t OFF_PROP   = 5226496;    // 589,824 -> 5,816,320
  const size_t OFF_KEYS   = 0;          // reuse (dead after conv1x1)
  const size_t OFF_TOPBOX = 524288;     // 96,000 -> 620,288
  const size_t OFF_MASK   = 620288;     // 94*6016*8 = 4,524,032 -> 5,144,320
  const size_t OFF_KEEPW  = 5144320;    // 752
  const size_t OFF_ROIBOX = 5145088;    // 32,000 -> 5,177,088
  const size_t OFF_PART   = 5816320;    // KS * 4MB split-K partials

  float* sharedb = (float*)(w + OFF_SHARED);
  float* cls     = (float*)(w + OFF_CLS);
  float* bbox    = (float*)(w + OFF_BBOX);
  float* scores  = (float*)(w + OFF_SCORES);
  float* prop    = (float*)(w + OFF_PROP);
  u64*   keys    = (u64*)(w + OFF_KEYS);
  float4* topbox = (float4*)(w + OFF_TOPBOX);
  u64*   maskT   = (u64*)(w + OFF_MASK);
  u64*   keepw   = (u64*)(w + OFF_KEEPW);
  float4* roibox = (float4*)(w + OFF_ROIBOX);
  float* out     = (float*)d_out;

  const size_t SLICE = (size_t)M_POS * NCH * 4;
  int KS = 1;
  if (ws_size >= OFF_PART + 8 * SLICE) KS = 8;
  else if (ws_size >= OFF_PART + 4 * SLICE) KS = 4;
  else if (ws_size >= OFF_PART + 2 * SLICE) KS = 2;
  float* part = (KS > 1) ? (float*)(w + OFF_PART) : sharedb;

  conv3x3<<<dim3(32, 2, KS), 256, 0, stream>>>(in, wsh, part, KTOT / KS);
  reduce_bias<<<4096, 256, 0, stream>>>(part, bsh, sharedb, KS);
  conv1x1<<<4096, 64, 0, stream>>>(sharedb, wcls, bcls, wbb, bbb, cls, bbox);
  proposals_k<<<144, 256, 0, stream>>>(cls, bbox, scores, prop);
  build_keys<<<256, 256, 0, stream>>>(scores, keys);
  sort_local<<<32, 1024, 0, stream>>>(keys);
  for (int k = 4096; k <= NSORT; k <<= 1) {
    int j = k >> 1;
    while (j >= 4096) {
      sort_gstep2<<<64, 256, 0, stream>>>(keys, k, j);
      j >>= 2;
    }
    if (j == 2048) {
      sort_gstep<<<128, 256, 0, stream>>>(keys, k, j);
      j >>= 1;
    }
    sort_lstep<<<32, 1024, 0, stream>>>(keys, k);
  }
  gather_top<<<24, 256, 0, stream>>>(keys, (const float4*)prop, topbox);
  nms_mask<<<dim3(NGRP, NGRP), 64, 0, stream>>>(topbox, maskT);
  nms_scan<<<1, 1024, 0, stream>>>(maskT, keepw);
  select_rois<<<1, 1024, 0, stream>>>(keepw, topbox, roibox);
  roi_sample<<<1, 1024, 0, stream>>>(roibox, gt, out);
}

// Round 8
// 759.271 us; speedup vs baseline: 3.8087x; 3.7971x over previous
//
#include <hip/hip_runtime.h>
#include <cstdint>
#include <cstddef>

#define M_POS 4096
#define NCH   256
#define KTOT  9216
#define NANCH 36864
#define NSORT 65536
#define PRE   6000
#define POST  2000
#define NGRP  94
#define MROW  6016  // padded maskT row stride (u64 elements)
#define NSLOT 14    // groups owned per pusher wave (7 pusher waves)

typedef unsigned long long u64;
typedef unsigned int u32;

__device__ __forceinline__ u32 ord_f32(float f) {
  u32 u = __float_as_uint(f);
  return (u & 0x80000000u) ? ~u : (u | 0x80000000u);
}

// ---------------- conv 3x3 as im2col GEMM: M=4096, N=256, K=9216 --------
// BM=128, BN=128, BK=16, 256 threads, 8x8 per thread (split 4+4 frags).
__global__ __launch_bounds__(256) void conv3x3(const float* __restrict__ in,
                                               const float* __restrict__ wgt,
                                               float* __restrict__ part,
                                               int kPer) {
  __shared__ __align__(16) float As[16][128];
  __shared__ __align__(16) float Bs[16][128];
  int tid = threadIdx.x;
  int bm = blockIdx.x << 7;
  int bn = blockIdx.y << 7;
  int kBeg = blockIdx.z * kPer;
  int am = tid & 127;
  int aq = (tid >> 7) << 2;
  int gm = bm + am;
  int y = gm >> 6, x = gm & 63;
  int bkk = tid >> 5;
  int bn4 = (tid & 31) << 2;
  int ty = tid >> 4, tx = tid & 15;

  float acc[8][8];
#pragma unroll
  for (int i = 0; i < 8; ++i)
#pragma unroll
    for (int j = 0; j < 8; ++j) acc[i][j] = 0.f;

  for (int k0 = kBeg; k0 < kBeg + kPer; k0 += 16) {
#pragma unroll
    for (int p = 0; p < 2; ++p) {
      int kk = aq + (p << 3);
      int k = k0 + kk;
      int tap = k >> 10;
      int c = k & 1023;
      int iy = y + tap / 3 - 1;
      int ix = x + tap % 3 - 1;
      float4 v = make_float4(0.f, 0.f, 0.f, 0.f);
      if (iy >= 0 && iy < 64 && ix >= 0 && ix < 64)
        v = *(const float4*)(in + (size_t)((((iy << 6) + ix) << 10) + c));
      As[kk + 0][am] = v.x;
      As[kk + 1][am] = v.y;
      As[kk + 2][am] = v.z;
      As[kk + 3][am] = v.w;
    }
#pragma unroll
    for (int p = 0; p < 2; ++p) {
      int kk = bkk + (p << 3);
      *(float4*)&Bs[kk][bn4] =
          *(const float4*)(wgt + (size_t)(k0 + kk) * NCH + bn + bn4);
    }
    __syncthreads();
#pragma unroll
    for (int kk = 0; kk < 16; ++kk) {
      float4 a0 = *(const float4*)&As[kk][ty << 2];
      float4 a1 = *(const float4*)&As[kk][64 + (ty << 2)];
      float4 b0 = *(const float4*)&Bs[kk][tx << 2];
      float4 b1 = *(const float4*)&Bs[kk][64 + (tx << 2)];
      float a[8] = {a0.x, a0.y, a0.z, a0.w, a1.x, a1.y, a1.z, a1.w};
      float b[8] = {b0.x, b0.y, b0.z, b0.w, b1.x, b1.y, b1.z, b1.w};
#pragma unroll
      for (int i = 0; i < 8; ++i)
#pragma unroll
        for (int j = 0; j < 8; ++j) acc[i][j] += a[i] * b[j];
    }
    __syncthreads();
  }
  size_t ob = (size_t)blockIdx.z * ((size_t)M_POS * NCH);
#pragma unroll
  for (int i = 0; i < 8; ++i) {
    int row = bm + ((i < 4) ? ((ty << 2) + i) : (64 + (ty << 2) + i - 4));
    float4 o0 = make_float4(acc[i][0], acc[i][1], acc[i][2], acc[i][3]);
    float4 o1 = make_float4(acc[i][4], acc[i][5], acc[i][6], acc[i][7]);
    *(float4*)(part + ob + (size_t)row * NCH + bn + (tx << 2)) = o0;
    *(float4*)(part + ob + (size_t)row * NCH + bn + 64 + (tx << 2)) = o1;
  }
}

__global__ __launch_bounds__(256) void reduce_bias(const float* __restrict__ part,
                                                   const float* __restrict__ bias,
                                                   float* __restrict__ outp, int ks) {
  int idx = blockIdx.x * 256 + threadIdx.x;
  float v = 0.f;
  for (int s = 0; s < ks; ++s) v += part[(size_t)s * (M_POS * NCH) + idx];
  outp[idx] = v + bias[idx & 255];
}

// ---------------- 1x1 conv heads: cls (256->18), bbox (256->36) ----------
__global__ __launch_bounds__(64) void conv1x1(const float* __restrict__ sh,
                                              const float* __restrict__ wc,
                                              const float* __restrict__ bc,
                                              const float* __restrict__ wb,
                                              const float* __restrict__ bb2,
                                              float* __restrict__ cls,
                                              float* __restrict__ bbox) {
  __shared__ float row[256];
  int pos = blockIdx.x;
  int tid = threadIdx.x;
  *(float4*)&row[tid * 4] = *(const float4*)(sh + (size_t)pos * 256 + tid * 4);
  __syncthreads();
  if (tid < 18) {
    float acc = bc[tid];
    for (int c = 0; c < 256; ++c) acc += row[c] * wc[c * 18 + tid];
    cls[(size_t)pos * 18 + tid] = acc;
  } else if (tid < 54) {
    int n = tid - 18;
    float acc = bb2[n];
    for (int c = 0; c < 256; ++c) acc += row[c] * wb[c * 36 + n];
    bbox[(size_t)pos * 36 + n] = acc;
  }
}

// ---------------- scores + box decode + clip -----------------------------
__global__ __launch_bounds__(256) void proposals_k(const float* __restrict__ cls,
                                                   const float* __restrict__ bb,
                                                   float* __restrict__ scores,
                                                   float* __restrict__ prop) {
  int idx = blockIdx.x * 256 + threadIdx.x;
  if (idx >= NANCH) return;
  int a = idx % 9;
  int pos = idx / 9;
  int x = pos & 63, y = pos >> 6;
  float s0 = cls[(size_t)pos * 18 + 2 * a];
  float s1 = cls[(size_t)pos * 18 + 2 * a + 1];
  float mx = fmaxf(s0, s1);
  float e0 = expf(s0 - mx), e1 = expf(s1 - mx);
  scores[idx] = e1 / (e0 + e1);
  const float AW[9] = {184.f, 368.f, 736.f, 128.f, 256.f, 512.f, 88.f, 176.f, 352.f};
  const float AH[9] = {96.f, 192.f, 384.f, 128.f, 256.f, 512.f, 176.f, 352.f, 704.f};
  float w = AW[a], h = AH[a];
  float cx = (float)(x * 16) + 8.0f;
  float cy = (float)(y * 16) + 8.0f;
  float dx = bb[(size_t)pos * 36 + 4 * a + 0];
  float dy = bb[(size_t)pos * 36 + 4 * a + 1];
  float dw = bb[(size_t)pos * 36 + 4 * a + 2];
  float dh = bb[(size_t)pos * 36 + 4 * a + 3];
  dw = fminf(fmaxf(dw, -4.135f), 4.135f);
  dh = fminf(fmaxf(dh, -4.135f), 4.135f);
  float pcx = dx * w + cx;
  float pcy = dy * h + cy;
  float pw = expf(dw) * w;
  float ph = expf(dh) * h;
  float x1 = pcx - 0.5f * pw, y1 = pcy - 0.5f * ph;
  float x2 = pcx + 0.5f * pw, y2 = pcy + 0.5f * ph;
  x1 = fminf(fmaxf(x1, 0.f), 1023.f);
  y1 = fminf(fmaxf(y1, 0.f), 1023.f);
  x2 = fminf(fmaxf(x2, 0.f), 1023.f);
  y2 = fminf(fmaxf(y2, 0.f), 1023.f);
  prop[(size_t)idx * 4 + 0] = x1;
  prop[(size_t)idx * 4 + 1] = y1;
  prop[(size_t)idx * 4 + 2] = x2;
  prop[(size_t)idx * 4 + 3] = y2;
}

// ---------------- composite sort keys (score desc, index asc) ------------
__global__ __launch_bounds__(256) void build_keys(const float* __restrict__ scores,
                                                  u64* __restrict__ keys) {
  int i = blockIdx.x * 256 + threadIdx.x;
  if (i >= NSORT) return;
  u64 k = 0ull;
  if (i < NANCH) {
    u32 u = ord_f32(scores[i]);
    k = ((u64)u << 32) | (u64)(0xFFFFFFFFu - (u32)i);
  }
  keys[i] = k;
}

// bitonic sort, DESCENDING. Direction: (i & k)==0 -> desc.
__global__ __launch_bounds__(1024) void sort_local(u64* keys) {
  __shared__ u64 s[2048];
  int base = blockIdx.x * 2048;
  s[threadIdx.x] = keys[base + threadIdx.x];
  s[threadIdx.x + 1024] = keys[base + threadIdx.x + 1024];
  __syncthreads();
  for (int k = 2; k <= 2048; k <<= 1) {
    for (int j = k >> 1; j >= 1; j >>= 1) {
      int t = threadIdx.x;
      int i = ((t & ~(j - 1)) << 1) | (t & (j - 1));
      int p = i | j;
      bool desc = (((base + i) & k) == 0);
      u64 a = s[i], b = s[p];
      if (desc ? (a < b) : (a > b)) { s[i] = b; s[p] = a; }
      __syncthreads();
    }
  }
  keys[base + threadIdx.x] = s[threadIdx.x];
  keys[base + threadIdx.x + 1024] = s[threadIdx.x + 1024];
}

__device__ __forceinline__ void cmpswap(u64& a, u64& b, bool desc) {
  if (desc ? (a < b) : (a > b)) { u64 t = a; a = b; b = t; }
}

__global__ __launch_bounds__(256) void sort_gstep(u64* keys, int k, int j) {
  int t = blockIdx.x * 256 + threadIdx.x;
  int i = ((t & ~(j - 1)) << 1) | (t & (j - 1));
  int p = i | j;
  bool desc = ((i & k) == 0);
  u64 a = keys[i], b = keys[p];
  if (desc ? (a < b) : (a > b)) { keys[i] = b; keys[p] = a; }
}

// two bitonic levels (j and j/2) per pass, 4 elements per thread
__global__ __launch_bounds__(256) void sort_gstep2(u64* keys, int k, int j) {
  int t = blockIdx.x * 256 + threadIdx.x; // NSORT/4 threads
  int j2 = j >> 1;
  int a = ((t & ~(j2 - 1)) << 1) | (t & (j2 - 1));
  int i0 = ((a & ~(j - 1)) << 1) | (a & (j - 1));
  int i1 = i0 | j2, i2 = i0 | j, i3 = i0 | j | j2;
  bool desc = ((i0 & k) == 0);
  u64 v0 = keys[i0], v1 = keys[i1], v2 = keys[i2], v3 = keys[i3];
  cmpswap(v0, v2, desc);
  cmpswap(v1, v3, desc);
  cmpswap(v0, v1, desc);
  cmpswap(v2, v3, desc);
  keys[i0] = v0; keys[i1] = v1; keys[i2] = v2; keys[i3] = v3;
}

__global__ __launch_bounds__(1024) void sort_lstep(u64* keys, int k) {
  __shared__ u64 s[2048];
  int base = blockIdx.x * 2048;
  s[threadIdx.x] = keys[base + threadIdx.x];
  s[threadIdx.x + 1024] = keys[base + threadIdx.x + 1024];
  __syncthreads();
  for (int j = 1024; j >= 1; j >>= 1) {
    int t = threadIdx.x;
    int i = ((t & ~(j - 1)) << 1) | (t & (j - 1));
    int p = i | j;
    bool desc = (((base + i) & k) == 0);
    u64 a = s[i], b = s[p];
    if (desc ? (a < b) : (a > b)) { s[i] = b; s[p] = a; }
    __syncthreads();
  }
  keys[base + threadIdx.x] = s[threadIdx.x];
  keys[base + threadIdx.x + 1024] = s[threadIdx.x + 1024];
}

__global__ __launch_bounds__(256) void gather_top(const u64* __restrict__ keys,
                                                  const float4* __restrict__ prop,
                                                  float4* __restrict__ topbox) {
  int i = blockIdx.x * 256 + threadIdx.x;
  if (i >= PRE) return;
  u64 kk = keys[i];
  u32 idx = 0xFFFFFFFFu - (u32)(kk & 0xFFFFFFFFull);
  topbox[i] = prop[idx];
}

// ------------- NMS suppression-mask matrix, TRANSPOSED: maskT[g][i] ------
// bit b of maskT[g*MROW + i] = (box i suppresses box g*64+b), i.e. iou>th & j>i
__global__ __launch_bounds__(64) void nms_mask(const float4* __restrict__ boxes,
                                               u64* __restrict__ maskT) {
  __shared__ float4 cb[64];
  int ci = blockIdx.x, ri = blockIdx.y;
  int t = threadIdx.x;
  int col = (ci << 6) + t;
  cb[t] = (col < PRE) ? boxes[col] : make_float4(0.f, 0.f, 0.f, 0.f);
  __syncthreads();
  int r = (ri << 6) + t;
  if (r >= PRE) return;
  float4 rb = boxes[r];
  float ra = (rb.z - rb.x + 1.f) * (rb.w - rb.y + 1.f);
  u64 bits = 0ull;
  for (int cc = 0; cc < 64; ++cc) {
    int j = (ci << 6) + cc;
    if (j > r && j < PRE) {
      float4 b = cb[cc];
      float ba = (b.z - b.x + 1.f) * (b.w - b.y + 1.f);
      float xx1 = fmaxf(rb.x, b.x), yy1 = fmaxf(rb.y, b.y);
      float xx2 = fminf(rb.z, b.z), yy2 = fminf(rb.w, b.w);
      float iw = fmaxf(xx2 - xx1 + 1.f, 0.f);
      float ih = fmaxf(yy2 - yy1 + 1.f, 0.f);
      float inter = iw * ih;
      float iou = inter / (ra + ba - inter);
      if (iou > 0.7f) bits |= (1ull << cc);
    }
  }
  maskT[(size_t)ci * MROW + r] = bits;
}

// ------------- greedy NMS scan v4: pipelined push, register-budget-aware --
// 512 threads (8 waves). Wave 0: serial scan with CHUNKED shfl hoist (mm[8],
// 16 VGPRs — no spill). Waves 1..7: own groups gp = wv + 7*i (14 slots),
// ext accumulators in registers (acc[14]+v[14] = 56 VGPRs), one predicated
// OR per round; 6-shfl reduce only at handoff. Loads issued one round ahead.
__global__ __launch_bounds__(512, 2) void nms_scan(const u64* __restrict__ maskT,
                                                   u64* __restrict__ keepw) {
  __shared__ u64 keepS;
  __shared__ u64 extS;
  const int tid = threadIdx.x;
  const int lane = tid & 63, wv = tid >> 6;  // wv in 0..7

  u64 acc[NSLOT], v[NSLOT];
#pragma unroll
  for (int i = 0; i < NSLOT; ++i) { acc[i] = 0ull; v[i] = 0ull; }

  // prologue: round-0 loads (column block 0) for owned gp >= 1
  if (wv > 0) {
#pragma unroll
    for (int i = 0; i < NSLOT; ++i) {
      int gp = wv + 7 * i;
      if (gp < NGRP) v[i] = maskT[(size_t)gp * MROW + lane];
    }
  }
  u64 x = 0ull;
  if (wv == 0) x = maskT[lane];  // intra row of group 0

  for (int g = 0; g < NGRP; ++g) {
    if (wv == 0) {
      u64 cur = (g == 0) ? 0ull : extS;
      u64 keep = 0ull;
      // chunked hoist: 8 independent shfls into mm[8] (static idx, 16 VGPRs),
      // then 8-step dependent VALU chain; next chunk's shfls overlap chain.
#pragma unroll
      for (int c = 0; c < 8; ++c) {
        u64 mm[8];
#pragma unroll
        for (int q = 0; q < 8; ++q) mm[q] = __shfl(x, (c << 3) + q, 64);
#pragma unroll
        for (int q = 0; q < 8; ++q) {
          int t = (c << 3) + q;
          if (!((cur >> t) & 1ull)) { keep |= (1ull << t); cur |= mm[q]; }
        }
      }
      if (g == NGRP - 1) keep &= (1ull << 48) - 1ull; // 6000 = 93*64+48
      if (lane == 0) { keepS = keep; keepw[g] = keep; }
      // prefetch intra row for g+1 (consumed next iteration)
      if (g + 1 < NGRP) {
        int ii = ((g + 1) << 6) + lane;
        x = (ii < PRE) ? maskT[(size_t)(g + 1) * MROW + ii] : 0ull;
      }
    }
    __syncthreads();  // keepS visible; extS (for g) consumed
    if (wv > 0) {
      u64 kb = keepS;
      u64 sel = ((kb >> lane) & 1ull) ? ~0ull : 0ull;
      u64 e = 0ull;
      bool own = false;
#pragma unroll
      for (int i = 0; i < NSLOT; ++i) {
        int gp = wv + 7 * i;
        if (gp < NGRP && gp > g) {
          acc[i] |= (v[i] & sel);
          if (gp == g + 1) { e = acc[i]; own = true; }
        }
      }
      if (own) {  // wave-uniform: exactly one wave owns g+1
#pragma unroll
        for (int s = 1; s < 64; s <<= 1) e |= __shfl_xor(e, s, 64);
        if (lane == 0) extS = e;
      }
      // issue loads for round g+1 (column block g+1), owned gp > g+1
      int col = ((g + 1) << 6) + lane;
#pragma unroll
      for (int i = 0; i < NSLOT; ++i) {
        int gp = wv + 7 * i;
        if (gp < NGRP && gp > g + 1) v[i] = maskT[(size_t)gp * MROW + col];
      }
    }
    __syncthreads();  // extS (for g+1) visible to wave 0
  }
}

// -------- sel = argsort(keep?idx:6000+idx)[:2000]; gather roi boxes ------
__global__ __launch_bounds__(1024) void select_rois(const u64* __restrict__ keepw,
                                                    const float4* __restrict__ topbox,
                                                    float4* __restrict__ roibox) {
  __shared__ u32 wscan[NGRP + 1];
  __shared__ u32 wc[NGRP];
  int tid = threadIdx.x;
  if (tid < NGRP) wc[tid] = (u32)__popcll(keepw[tid]);
  __syncthreads();
  if (tid == 0) {
    u32 r = 0;
    for (int g = 0; g < NGRP; ++g) { wscan[g] = r; r += wc[g]; }
    wscan[NGRP] = r;
  }
  __syncthreads();
  u32 ktot = wscan[NGRP];
  for (int i = tid; i < PRE; i += 1024) {
    int g = i >> 6, t = i & 63;
    u64 w = keepw[g];
    bool kept = (w >> t) & 1ull;
    u32 pk = wscan[g] + (u32)__popcll(w & ((1ull << t) - 1ull));
    u32 pos = kept ? pk : (ktot + (u32)i - pk);
    if (pos < POST) roibox[pos] = topbox[i];
  }
}

// ---------------- ROI sampling: IoU vs gt, fg/bg stable top-k ------------
__device__ void bitonic2048_desc(u64* s) {
  int tid = threadIdx.x;
  for (int k = 2; k <= 2048; k <<= 1) {
    for (int j = k >> 1; j >= 1; j >>= 1) {
      int i = ((tid & ~(j - 1)) << 1) | (tid & (j - 1));
      int p = i | j;
      bool desc = ((i & k) == 0);
      u64 a = s[i], b = s[p];
      if (desc ? (a < b) : (a > b)) { s[i] = b; s[p] = a; }
      __syncthreads();
    }
  }
}

__global__ __launch_bounds__(1024) void roi_sample(const float4* __restrict__ roibox,
                                                   const float* __restrict__ gt,
                                                   float* __restrict__ out) {
  __shared__ float mov[POST];
  __shared__ u64 sk[2048];
  __shared__ float gtb[20][4];
  __shared__ int fgsel[32];
  __shared__ int bgsel[96];
  int tid = threadIdx.x;
  if (tid < 20) {
    gtb[tid][0] = gt[tid * 5 + 0];
    gtb[tid][1] = gt[tid * 5 + 1];
    gtb[tid][2] = gt[tid * 5 + 2];
    gtb[tid][3] = gt[tid * 5 + 3];
  }
  __syncthreads();
  for (int i = tid; i < POST; i += 1024) {
    float4 b = roibox[i];
    float aa = (b.z - b.x + 1.f) * (b.w - b.y + 1.f);
    float m = -3.402823466e38f;
    for (int t = 0; t < 20; ++t) {
      float gx1 = gtb[t][0], gy1 = gtb[t][1], gx2 = gtb[t][2], gy2 = gtb[t][3];
      float ga = (gx2 - gx1 + 1.f) * (gy2 - gy1 + 1.f);
      float xx1 = fmaxf(b.x, gx1), yy1 = fmaxf(b.y, gy1);
      float xx2 = fminf(b.z, gx2), yy2 = fminf(b.w, gy2);
      float iw = fmaxf(xx2 - xx1 + 1.f, 0.f);
      float ih = fmaxf(yy2 - yy1 + 1.f, 0.f);
      float inter = iw * ih;
      float iou = inter / (aa + ga - inter);
      m = fmaxf(m, iou);
    }
    mov[i] = m;
  }
  __syncthreads();
  for (int i = tid; i < 2048; i += 1024) {
    float key;
    if (i < POST) { float v = mov[i]; key = (v >= 0.5f) ? v : -1.0f; }
    else key = -2.0f;
    sk[i] = ((u64)ord_f32(key) << 32) | (u64)(2047u - (u32)i);
  }
  __syncthreads();
  bitonic2048_desc(sk);
  if (tid < 32) fgsel[tid] = (int)(2047u - (u32)(sk[tid] & 0xFFFFFFFFull));
  __syncthreads();
  for (int i = tid; i < 2048; i += 1024) {
    float key;
    if (i < POST) {
      float v = mov[i];
      key = (v < 0.5f && v >= 0.1f) ? v : -1.0f;
    } else key = -2.0f;
    sk[i] = ((u64)ord_f32(key) << 32) | (u64)(2047u - (u32)i);
  }
  __syncthreads();
  bitonic2048_desc(sk);
  if (tid < 96) bgsel[tid] = (int)(2047u - (u32)(sk[tid] & 0xFFFFFFFFull));
  __syncthreads();
  if (tid < 128) {
    int idx = (tid < 32) ? fgsel[tid] : bgsel[tid - 32];
    float4 b = roibox[idx];
    out[tid * 5 + 0] = 0.f;
    out[tid * 5 + 1] = b.x;
    out[tid * 5 + 2] = b.y;
    out[tid * 5 + 3] = b.z;
    out[tid * 5 + 4] = b.w;
  }
}

// ---------------- host launch ----------------
extern "C" void kernel_launch(void* const* d_in, const int* in_sizes, int n_in,
                              void* d_out, int out_size, void* d_ws, size_t ws_size,
                              hipStream_t stream) {
  const float* in   = (const float*)d_in[0];
  const float* wsh  = (const float*)d_in[1];
  const float* bsh  = (const float*)d_in[2];
  const float* wcls = (const float*)d_in[3];
  const float* bcls = (const float*)d_in[4];
  const float* wbb  = (const float*)d_in[5];
  const float* bbb  = (const float*)d_in[6];
  const float* gt   = (const float*)d_in[7];

  char* w = (char*)d_ws;
  const size_t OFF_SHARED = 0;          // 4,194,304 conv out (also keys later)
  const size_t OFF_CLS    = 4194304;    // 294,912
  const size_t OFF_BBOX   = 4489216;    // 589,824
  const size_t OFF_SCORES = 5079040;    // 147,456
  const size_t OFF_PROP   = 5226496;    // 589,824 -> 5,816,320
  const size_t OFF_KEYS   = 0;          // reuse (dead after conv1x1)
  const size_t OFF_TOPBOX = 524288;     // 96,000 -> 620,288
  const size_t OFF_MASK   = 620288;     // 94*6016*8 = 4,524,032 -> 5,144,320
  const size_t OFF_KEEPW  = 5144320;    // 752
  const size_t OFF_ROIBOX = 5145088;    // 32,000 -> 5,177,088
  const size_t OFF_PART   = 5816320;    // KS * 4MB split-K partials

  float* sharedb = (float*)(w + OFF_SHARED);
  float* cls     = (float*)(w + OFF_CLS);
  float* bbox    = (float*)(w + OFF_BBOX);
  float* scores  = (float*)(w + OFF_SCORES);
  float* prop    = (float*)(w + OFF_PROP);
  u64*   keys    = (u64*)(w + OFF_KEYS);
  float4* topbox = (float4*)(w + OFF_TOPBOX);
  u64*   maskT   = (u64*)(w + OFF_MASK);
  u64*   keepw   = (u64*)(w + OFF_KEEPW);
  float4* roibox = (float4*)(w + OFF_ROIBOX);
  float* out     = (float*)d_out;

  const size_t SLICE = (size_t)M_POS * NCH * 4;
  int KS = 1;
  if (ws_size >= OFF_PART + 8 * SLICE) KS = 8;
  else if (ws_size >= OFF_PART + 4 * SLICE) KS = 4;
  else if (ws_size >= OFF_PART + 2 * SLICE) KS = 2;
  float* part = (KS > 1) ? (float*)(w + OFF_PART) : sharedb;

  conv3x3<<<dim3(32, 2, KS), 256, 0, stream>>>(in, wsh, part, KTOT / KS);
  reduce_bias<<<4096, 256, 0, stream>>>(part, bsh, sharedb, KS);
  conv1x1<<<4096, 64, 0, stream>>>(sharedb, wcls, bcls, wbb, bbb, cls, bbox);
  proposals_k<<<144, 256, 0, stream>>>(cls, bbox, scores, prop);
  build_keys<<<256, 256, 0, stream>>>(scores, keys);
  sort_local<<<32, 1024, 0, stream>>>(keys);
  for (int k = 4096; k <= NSORT; k <<= 1) {
    int j = k >> 1;
    while (j >= 4096) {
      sort_gstep2<<<64, 256, 0, stream>>>(keys, k, j);
      j >>= 2;
    }
    if (j == 2048) {
      sort_gstep<<<128, 256, 0, stream>>>(keys, k, j);
      j >>= 1;
    }
    sort_lstep<<<32, 1024, 0, stream>>>(keys, k);
  }
  gather_top<<<24, 256, 0, stream>>>(keys, (const float4*)prop, topbox);
  nms_mask<<<dim3(NGRP, NGRP), 64, 0, stream>>>(topbox, maskT);
  nms_scan<<<1, 512, 0, stream>>>(maskT, keepw);
  select_rois<<<1, 1024, 0, stream>>>(keepw, topbox, roibox);
  roi_sample<<<1, 1024, 0, stream>>>(roibox, gt, out);
}

// Round 9
// 575.823 us; speedup vs baseline: 5.0221x; 1.3186x over previous
//
#include <hip/hip_runtime.h>
#include <cstdint>
#include <cstddef>

#define M_POS 4096
#define NCH   256
#define KTOT  9216
#define NANCH 36864
#define NSORT 65536
#define PRE   6000
#define POST  2000
#define NGRP  94
#define MROW  6016  // padded maskT row stride (u64 elements)
#define NSLOT 14    // groups owned per pusher wave (7 pusher waves)

typedef unsigned long long u64;
typedef unsigned int u32;

__device__ __forceinline__ u32 ord_f32(float f) {
  u32 u = __float_as_uint(f);
  return (u & 0x80000000u) ? ~u : (u | 0x80000000u);
}

// ---------------- conv 3x3 as im2col GEMM: M=4096, N=256, K=9216 --------
// BM=128, BN=128, BK=16, 256 threads, 8x8 per thread (split 4+4 frags).
__global__ __launch_bounds__(256) void conv3x3(const float* __restrict__ in,
                                               const float* __restrict__ wgt,
                                               float* __restrict__ part,
                                               int kPer) {
  __shared__ __align__(16) float As[16][128];
  __shared__ __align__(16) float Bs[16][128];
  int tid = threadIdx.x;
  int bm = blockIdx.x << 7;
  int bn = blockIdx.y << 7;
  int kBeg = blockIdx.z * kPer;
  int am = tid & 127;
  int aq = (tid >> 7) << 2;
  int gm = bm + am;
  int y = gm >> 6, x = gm & 63;
  int bkk = tid >> 5;
  int bn4 = (tid & 31) << 2;
  int ty = tid >> 4, tx = tid & 15;

  float acc[8][8];
#pragma unroll
  for (int i = 0; i < 8; ++i)
#pragma unroll
    for (int j = 0; j < 8; ++j) acc[i][j] = 0.f;

  for (int k0 = kBeg; k0 < kBeg + kPer; k0 += 16) {
#pragma unroll
    for (int p = 0; p < 2; ++p) {
      int kk = aq + (p << 3);
      int k = k0 + kk;
      int tap = k >> 10;
      int c = k & 1023;
      int iy = y + tap / 3 - 1;
      int ix = x + tap % 3 - 1;
      float4 v = make_float4(0.f, 0.f, 0.f, 0.f);
      if (iy >= 0 && iy < 64 && ix >= 0 && ix < 64)
        v = *(const float4*)(in + (size_t)((((iy << 6) + ix) << 10) + c));
      As[kk + 0][am] = v.x;
      As[kk + 1][am] = v.y;
      As[kk + 2][am] = v.z;
      As[kk + 3][am] = v.w;
    }
#pragma unroll
    for (int p = 0; p < 2; ++p) {
      int kk = bkk + (p << 3);
      *(float4*)&Bs[kk][bn4] =
          *(const float4*)(wgt + (size_t)(k0 + kk) * NCH + bn + bn4);
    }
    __syncthreads();
#pragma unroll
    for (int kk = 0; kk < 16; ++kk) {
      float4 a0 = *(const float4*)&As[kk][ty << 2];
      float4 a1 = *(const float4*)&As[kk][64 + (ty << 2)];
      float4 b0 = *(const float4*)&Bs[kk][tx << 2];
      float4 b1 = *(const float4*)&Bs[kk][64 + (tx << 2)];
      float a[8] = {a0.x, a0.y, a0.z, a0.w, a1.x, a1.y, a1.z, a1.w};
      float b[8] = {b0.x, b0.y, b0.z, b0.w, b1.x, b1.y, b1.z, b1.w};
#pragma unroll
      for (int i = 0; i < 8; ++i)
#pragma unroll
        for (int j = 0; j < 8; ++j) acc[i][j] += a[i] * b[j];
    }
    __syncthreads();
  }
  size_t ob = (size_t)blockIdx.z * ((size_t)M_POS * NCH);
#pragma unroll
  for (int i = 0; i < 8; ++i) {
    int row = bm + ((i < 4) ? ((ty << 2) + i) : (64 + (ty << 2) + i - 4));
    float4 o0 = make_float4(acc[i][0], acc[i][1], acc[i][2], acc[i][3]);
    float4 o1 = make_float4(acc[i][4], acc[i][5], acc[i][6], acc[i][7]);
    *(float4*)(part + ob + (size_t)row * NCH + bn + (tx << 2)) = o0;
    *(float4*)(part + ob + (size_t)row * NCH + bn + 64 + (tx << 2)) = o1;
  }
}

__global__ __launch_bounds__(256) void reduce_bias(const float* __restrict__ part,
                                                   const float* __restrict__ bias,
                                                   float* __restrict__ outp, int ks) {
  int idx = blockIdx.x * 256 + threadIdx.x;
  float v = 0.f;
  for (int s = 0; s < ks; ++s) v += part[(size_t)s * (M_POS * NCH) + idx];
  outp[idx] = v + bias[idx & 255];
}

// ---------------- 1x1 conv heads: cls (256->18), bbox (256->36) ----------
__global__ __launch_bounds__(64) void conv1x1(const float* __restrict__ sh,
                                              const float* __restrict__ wc,
                                              const float* __restrict__ bc,
                                              const float* __restrict__ wb,
                                              const float* __restrict__ bb2,
                                              float* __restrict__ cls,
                                              float* __restrict__ bbox) {
  __shared__ float row[256];
  int pos = blockIdx.x;
  int tid = threadIdx.x;
  *(float4*)&row[tid * 4] = *(const float4*)(sh + (size_t)pos * 256 + tid * 4);
  __syncthreads();
  if (tid < 18) {
    float acc = bc[tid];
    for (int c = 0; c < 256; ++c) acc += row[c] * wc[c * 18 + tid];
    cls[(size_t)pos * 18 + tid] = acc;
  } else if (tid < 54) {
    int n = tid - 18;
    float acc = bb2[n];
    for (int c = 0; c < 256; ++c) acc += row[c] * wb[c * 36 + n];
    bbox[(size_t)pos * 36 + n] = acc;
  }
}

// ---------------- scores + box decode + clip -----------------------------
__global__ __launch_bounds__(256) void proposals_k(const float* __restrict__ cls,
                                                   const float* __restrict__ bb,
                                                   float* __restrict__ scores,
                                                   float* __restrict__ prop) {
  int idx = blockIdx.x * 256 + threadIdx.x;
  if (idx >= NANCH) return;
  int a = idx % 9;
  int pos = idx / 9;
  int x = pos & 63, y = pos >> 6;
  float s0 = cls[(size_t)pos * 18 + 2 * a];
  float s1 = cls[(size_t)pos * 18 + 2 * a + 1];
  float mx = fmaxf(s0, s1);
  float e0 = expf(s0 - mx), e1 = expf(s1 - mx);
  scores[idx] = e1 / (e0 + e1);
  const float AW[9] = {184.f, 368.f, 736.f, 128.f, 256.f, 512.f, 88.f, 176.f, 352.f};
  const float AH[9] = {96.f, 192.f, 384.f, 128.f, 256.f, 512.f, 176.f, 352.f, 704.f};
  float w = AW[a], h = AH[a];
  float cx = (float)(x * 16) + 8.0f;
  float cy = (float)(y * 16) + 8.0f;
  float dx = bb[(size_t)pos * 36 + 4 * a + 0];
  float dy = bb[(size_t)pos * 36 + 4 * a + 1];
  float dw = bb[(size_t)pos * 36 + 4 * a + 2];
  float dh = bb[(size_t)pos * 36 + 4 * a + 3];
  dw = fminf(fmaxf(dw, -4.135f), 4.135f);
  dh = fminf(fmaxf(dh, -4.135f), 4.135f);
  float pcx = dx * w + cx;
  float pcy = dy * h + cy;
  float pw = expf(dw) * w;
  float ph = expf(dh) * h;
  float x1 = pcx - 0.5f * pw, y1 = pcy - 0.5f * ph;
  float x2 = pcx + 0.5f * pw, y2 = pcy + 0.5f * ph;
  x1 = fminf(fmaxf(x1, 0.f), 1023.f);
  y1 = fminf(fmaxf(y1, 0.f), 1023.f);
  x2 = fminf(fmaxf(x2, 0.f), 1023.f);
  y2 = fminf(fmaxf(y2, 0.f), 1023.f);
  prop[(size_t)idx * 4 + 0] = x1;
  prop[(size_t)idx * 4 + 1] = y1;
  prop[(size_t)idx * 4 + 2] = x2;
  prop[(size_t)idx * 4 + 3] = y2;
}

// ---------------- composite sort keys (score desc, index asc) ------------
__global__ __launch_bounds__(256) void build_keys(const float* __restrict__ scores,
                                                  u64* __restrict__ keys) {
  int i = blockIdx.x * 256 + threadIdx.x;
  if (i >= NSORT) return;
  u64 k = 0ull;
  if (i < NANCH) {
    u32 u = ord_f32(scores[i]);
    k = ((u64)u << 32) | (u64)(0xFFFFFFFFu - (u32)i);
  }
  keys[i] = k;
}

// bitonic sort, DESCENDING. Direction: (i & k)==0 -> desc.
__global__ __launch_bounds__(1024) void sort_local(u64* keys) {
  __shared__ u64 s[2048];
  int base = blockIdx.x * 2048;
  s[threadIdx.x] = keys[base + threadIdx.x];
  s[threadIdx.x + 1024] = keys[base + threadIdx.x + 1024];
  __syncthreads();
  for (int k = 2; k <= 2048; k <<= 1) {
    for (int j = k >> 1; j >= 1; j >>= 1) {
      int t = threadIdx.x;
      int i = ((t & ~(j - 1)) << 1) | (t & (j - 1));
      int p = i | j;
      bool desc = (((base + i) & k) == 0);
      u64 a = s[i], b = s[p];
      if (desc ? (a < b) : (a > b)) { s[i] = b; s[p] = a; }
      __syncthreads();
    }
  }
  keys[base + threadIdx.x] = s[threadIdx.x];
  keys[base + threadIdx.x + 1024] = s[threadIdx.x + 1024];
}

__device__ __forceinline__ void cmpswap(u64& a, u64& b, bool desc) {
  if (desc ? (a < b) : (a > b)) { u64 t = a; a = b; b = t; }
}

__global__ __launch_bounds__(256) void sort_gstep(u64* keys, int k, int j) {
  int t = blockIdx.x * 256 + threadIdx.x;
  int i = ((t & ~(j - 1)) << 1) | (t & (j - 1));
  int p = i | j;
  bool desc = ((i & k) == 0);
  u64 a = keys[i], b = keys[p];
  if (desc ? (a < b) : (a > b)) { keys[i] = b; keys[p] = a; }
}

// two bitonic levels (j and j/2) per pass, 4 elements per thread
__global__ __launch_bounds__(256) void sort_gstep2(u64* keys, int k, int j) {
  int t = blockIdx.x * 256 + threadIdx.x; // NSORT/4 threads
  int j2 = j >> 1;
  int a = ((t & ~(j2 - 1)) << 1) | (t & (j2 - 1));
  int i0 = ((a & ~(j - 1)) << 1) | (a & (j - 1));
  int i1 = i0 | j2, i2 = i0 | j, i3 = i0 | j | j2;
  bool desc = ((i0 & k) == 0);
  u64 v0 = keys[i0], v1 = keys[i1], v2 = keys[i2], v3 = keys[i3];
  cmpswap(v0, v2, desc);
  cmpswap(v1, v3, desc);
  cmpswap(v0, v1, desc);
  cmpswap(v2, v3, desc);
  keys[i0] = v0; keys[i1] = v1; keys[i2] = v2; keys[i3] = v3;
}

__global__ __launch_bounds__(1024) void sort_lstep(u64* keys, int k) {
  __shared__ u64 s[2048];
  int base = blockIdx.x * 2048;
  s[threadIdx.x] = keys[base + threadIdx.x];
  s[threadIdx.x + 1024] = keys[base + threadIdx.x + 1024];
  __syncthreads();
  for (int j = 1024; j >= 1; j >>= 1) {
    int t = threadIdx.x;
    int i = ((t & ~(j - 1)) << 1) | (t & (j - 1));
    int p = i | j;
    bool desc = (((base + i) & k) == 0);
    u64 a = s[i], b = s[p];
    if (desc ? (a < b) : (a > b)) { s[i] = b; s[p] = a; }
    __syncthreads();
  }
  keys[base + threadIdx.x] = s[threadIdx.x];
  keys[base + threadIdx.x + 1024] = s[threadIdx.x + 1024];
}

__global__ __launch_bounds__(256) void gather_top(const u64* __restrict__ keys,
                                                  const float4* __restrict__ prop,
                                                  float4* __restrict__ topbox) {
  int i = blockIdx.x * 256 + threadIdx.x;
  if (i >= PRE) return;
  u64 kk = keys[i];
  u32 idx = 0xFFFFFFFFu - (u32)(kk & 0xFFFFFFFFull);
  topbox[i] = prop[idx];
}

// ------------- NMS suppression-mask matrix, TRANSPOSED: maskT[g][i] ------
// bit b of maskT[g*MROW + i] = (box i suppresses box g*64+b), i.e. iou>th & j>i
__global__ __launch_bounds__(64) void nms_mask(const float4* __restrict__ boxes,
                                               u64* __restrict__ maskT) {
  __shared__ float4 cb[64];
  int ci = blockIdx.x, ri = blockIdx.y;
  int t = threadIdx.x;
  int col = (ci << 6) + t;
  cb[t] = (col < PRE) ? boxes[col] : make_float4(0.f, 0.f, 0.f, 0.f);
  __syncthreads();
  int r = (ri << 6) + t;
  if (r >= PRE) return;
  float4 rb = boxes[r];
  float ra = (rb.z - rb.x + 1.f) * (rb.w - rb.y + 1.f);
  u64 bits = 0ull;
  for (int cc = 0; cc < 64; ++cc) {
    int j = (ci << 6) + cc;
    if (j > r && j < PRE) {
      float4 b = cb[cc];
      float ba = (b.z - b.x + 1.f) * (b.w - b.y + 1.f);
      float xx1 = fmaxf(rb.x, b.x), yy1 = fmaxf(rb.y, b.y);
      float xx2 = fminf(rb.z, b.z), yy2 = fminf(rb.w, b.w);
      float iw = fmaxf(xx2 - xx1 + 1.f, 0.f);
      float ih = fmaxf(yy2 - yy1 + 1.f, 0.f);
      float inter = iw * ih;
      float iou = inter / (ra + ba - inter);
      if (iou > 0.7f) bits |= (1ull << cc);
    }
  }
  maskT[(size_t)ci * MROW + r] = bits;
}

// ------------- greedy NMS scan v5: raw barriers (no vmcnt drain) + SALU ---
// Same dataflow as v4 (proven correct). Changes:
//  * __syncthreads -> raw s_barrier + explicit lgkmcnt(0) + sched_barrier(0):
//    global prefetch loads stay in flight across rounds (no vmcnt(0) drain).
//  * wave0 serial chain in SGPRs: v_readlane hoist + s_cselect/s_or chain.
//  * early exit once cumulative kept >= POST (prefix property: output fixed).
__global__ __launch_bounds__(512, 2) void nms_scan(const u64* __restrict__ maskT,
                                                   u64* __restrict__ keepw) {
  __shared__ u64 keepS;
  __shared__ u64 extS;
  __shared__ u32 exitS;
  const int tid = threadIdx.x;
  const int lane = tid & 63, wv = tid >> 6;  // wv in 0..7

  u64 acc[NSLOT], v[NSLOT];
#pragma unroll
  for (int i = 0; i < NSLOT; ++i) { acc[i] = 0ull; v[i] = 0ull; }

  // prologue: round-0 loads (column block 0) for owned gp >= 1
  if (wv > 0) {
#pragma unroll
    for (int i = 0; i < NSLOT; ++i) {
      int gp = wv + 7 * i;
      if (gp < NGRP) v[i] = maskT[(size_t)gp * MROW + lane];
    }
  }
  u64 x = 0ull;
  if (wv == 0) x = maskT[lane];  // intra row of group 0
  u32 keptTot = 0;

  for (int g = 0; g < NGRP; ++g) {
    if (wv == 0) {
      u64 cur = 0ull;
      if (g > 0) {
        u64 e = extS;
        u32 elo = __builtin_amdgcn_readfirstlane((u32)(e & 0xFFFFFFFFull));
        u32 ehi = __builtin_amdgcn_readfirstlane((u32)(e >> 32));
        cur = ((u64)ehi << 32) | (u64)elo;
      }
      u32 xlo = (u32)(x & 0xFFFFFFFFull);
      u32 xhi = (u32)(x >> 32);
      u64 keep = 0ull;
#pragma unroll
      for (int t = 0; t < 64; ++t) {
        u32 mlo = __builtin_amdgcn_readlane(xlo, t);
        u32 mhi = __builtin_amdgcn_readlane(xhi, t);
        u64 mt = ((u64)mhi << 32) | (u64)mlo;
        u64 sup = (cur >> t) & 1ull;
        u64 sel = sup - 1ull;            // sup?0:~0 (branch-free, SALU)
        keep |= (1ull << t) & sel;
        cur |= mt & sel;
      }
      if (g == NGRP - 1) keep &= (1ull << 48) - 1ull; // 6000 = 93*64+48
      keptTot += (u32)__popcll(keep);
      if (lane == 0) {
        keepS = keep;
        exitS = (keptTot >= POST) ? 1u : 0u;
        keepw[g] = keep;
      }
      // prefetch intra row for g+1 (consumed next round; never drained)
      if (g + 1 < NGRP) {
        int ii = ((g + 1) << 6) + lane;
        x = (ii < PRE) ? maskT[(size_t)(g + 1) * MROW + ii] : 0ull;
      }
    }
    // ---- barrier 1: raw (no vmcnt drain); LDS publish fenced ----
    asm volatile("s_waitcnt lgkmcnt(0)" ::: "memory");
    __builtin_amdgcn_sched_barrier(0);
    __builtin_amdgcn_s_barrier();
    __builtin_amdgcn_sched_barrier(0);
    u32 ex = exitS;
    u64 kb = keepS;
    if (ex) {  // uniform across block: output for roibox[0..POST-1] is fixed
      for (int z = g + 1 + tid; z < NGRP; z += 512) keepw[z] = 0ull;
      return;
    }
    if (wv > 0) {
      u64 sel2 = ((kb >> lane) & 1ull) ? ~0ull : 0ull;
      u64 e = 0ull;
      bool own = false;
#pragma unroll
      for (int i = 0; i < NSLOT; ++i) {
        int gp = wv + 7 * i;
        if (gp < NGRP && gp > g) {
          acc[i] |= (v[i] & sel2);
          if (gp == g + 1) { e = acc[i]; own = true; }
        }
      }
      if (own) {  // wave-uniform: exactly one wave owns g+1
#pragma unroll
        for (int s = 1; s < 64; s <<= 1) e |= __shfl_xor(e, s, 64);
        if (lane == 0) extS = e;
      }
      // issue loads for round g+1 (column block g+1), owned gp > g+1
      int col = ((g + 1) << 6) + lane;
#pragma unroll
      for (int i = 0; i < NSLOT; ++i) {
        int gp = wv + 7 * i;
        if (gp < NGRP && gp > g + 1) v[i] = maskT[(size_t)gp * MROW + col];
      }
    }
    // ---- barrier 2: raw; extS publish fenced ----
    asm volatile("s_waitcnt lgkmcnt(0)" ::: "memory");
    __builtin_amdgcn_sched_barrier(0);
    __builtin_amdgcn_s_barrier();
    __builtin_amdgcn_sched_barrier(0);
  }
}

// -------- sel = argsort(keep?idx:6000+idx)[:2000]; gather roi boxes ------
__global__ __launch_bounds__(1024) void select_rois(const u64* __restrict__ keepw,
                                                    const float4* __restrict__ topbox,
                                                    float4* __restrict__ roibox) {
  __shared__ u32 wscan[NGRP + 1];
  __shared__ u32 wc[NGRP];
  int tid = threadIdx.x;
  if (tid < NGRP) wc[tid] = (u32)__popcll(keepw[tid]);
  __syncthreads();
  if (tid == 0) {
    u32 r = 0;
    for (int g = 0; g < NGRP; ++g) { wscan[g] = r; r += wc[g]; }
    wscan[NGRP] = r;
  }
  __syncthreads();
  u32 ktot = wscan[NGRP];
  for (int i = tid; i < PRE; i += 1024) {
    int g = i >> 6, t = i & 63;
    u64 w = keepw[g];
    bool kept = (w >> t) & 1ull;
    u32 pk = wscan[g] + (u32)__popcll(w & ((1ull << t) - 1ull));
    u32 pos = kept ? pk : (ktot + (u32)i - pk);
    if (pos < POST) roibox[pos] = topbox[i];
  }
}

// ---------------- ROI sampling: IoU vs gt, fg/bg stable top-k ------------
__device__ void bitonic2048_desc(u64* s) {
  int tid = threadIdx.x;
  for (int k = 2; k <= 2048; k <<= 1) {
    for (int j = k >> 1; j >= 1; j >>= 1) {
      int i = ((tid & ~(j - 1)) << 1) | (tid & (j - 1));
      int p = i | j;
      bool desc = ((i & k) == 0);
      u64 a = s[i], b = s[p];
      if (desc ? (a < b) : (a > b)) { s[i] = b; s[p] = a; }
      __syncthreads();
    }
  }
}

__global__ __launch_bounds__(1024) void roi_sample(const float4* __restrict__ roibox,
                                                   const float* __restrict__ gt,
                                                   float* __restrict__ out) {
  __shared__ float mov[POST];
  __shared__ u64 sk[2048];
  __shared__ float gtb[20][4];
  __shared__ int fgsel[32];
  __shared__ int bgsel[96];
  int tid = threadIdx.x;
  if (tid < 20) {
    gtb[tid][0] = gt[tid * 5 + 0];
    gtb[tid][1] = gt[tid * 5 + 1];
    gtb[tid][2] = gt[tid * 5 + 2];
    gtb[tid][3] = gt[tid * 5 + 3];
  }
  __syncthreads();
  for (int i = tid; i < POST; i += 1024) {
    float4 b = roibox[i];
    float aa = (b.z - b.x + 1.f) * (b.w - b.y + 1.f);
    float m = -3.402823466e38f;
    for (int t = 0; t < 20; ++t) {
      float gx1 = gtb[t][0], gy1 = gtb[t][1], gx2 = gtb[t][2], gy2 = gtb[t][3];
      float ga = (gx2 - gx1 + 1.f) * (gy2 - gy1 + 1.f);
      float xx1 = fmaxf(b.x, gx1), yy1 = fmaxf(b.y, gy1);
      float xx2 = fminf(b.z, gx2), yy2 = fminf(b.w, gy2);
      float iw = fmaxf(xx2 - xx1 + 1.f, 0.f);
      float ih = fmaxf(yy2 - yy1 + 1.f, 0.f);
      float inter = iw * ih;
      float iou = inter / (aa + ga - inter);
      m = fmaxf(m, iou);
    }
    mov[i] = m;
  }
  __syncthreads();
  for (int i = tid; i < 2048; i += 1024) {
    float key;
    if (i < POST) { float v = mov[i]; key = (v >= 0.5f) ? v : -1.0f; }
    else key = -2.0f;
    sk[i] = ((u64)ord_f32(key) << 32) | (u64)(2047u - (u32)i);
  }
  __syncthreads();
  bitonic2048_desc(sk);
  if (tid < 32) fgsel[tid] = (int)(2047u - (u32)(sk[tid] & 0xFFFFFFFFull));
  __syncthreads();
  for (int i = tid; i < 2048; i += 1024) {
    float key;
    if (i < POST) {
      float v = mov[i];
      key = (v < 0.5f && v >= 0.1f) ? v : -1.0f;
    } else key = -2.0f;
    sk[i] = ((u64)ord_f32(key) << 32) | (u64)(2047u - (u32)i);
  }
  __syncthreads();
  bitonic2048_desc(sk);
  if (tid < 96) bgsel[tid] = (int)(2047u - (u32)(sk[tid] & 0xFFFFFFFFull));
  __syncthreads();
  if (tid < 128) {
    int idx = (tid < 32) ? fgsel[tid] : bgsel[tid - 32];
    float4 b = roibox[idx];
    out[tid * 5 + 0] = 0.f;
    out[tid * 5 + 1] = b.x;
    out[tid * 5 + 2] = b.y;
    out[tid * 5 + 3] = b.z;
    out[tid * 5 + 4] = b.w;
  }
}

// ---------------- host launch ----------------
extern "C" void kernel_launch(void* const* d_in, const int* in_sizes, int n_in,
                              void* d_out, int out_size, void* d_ws, size_t ws_size,
                              hipStream_t stream) {
  const float* in   = (const float*)d_in[0];
  const float* wsh  = (const float*)d_in[1];
  const float* bsh  = (const float*)d_in[2];
  const float* wcls = (const float*)d_in[3];
  const float* bcls = (const float*)d_in[4];
  const float* wbb  = (const float*)d_in[5];
  const float* bbb  = (const float*)d_in[6];
  const float* gt   = (const float*)d_in[7];

  char* w = (char*)d_ws;
  const size_t OFF_SHARED = 0;          // 4,194,304 conv out (also keys later)
  const size_t OFF_CLS    = 4194304;    // 294,912
  const size_t OFF_BBOX   = 4489216;    // 589,824
  const size_t OFF_SCORES = 5079040;    // 147,456
  const size_t OFF_PROP   = 5226496;    // 589,824 -> 5,816,320
  const size_t OFF_KEYS   = 0;          // reuse (dead after conv1x1)
  const size_t OFF_TOPBOX = 524288;     // 96,000 -> 620,288
  const size_t OFF_MASK   = 620288;     // 94*6016*8 = 4,524,032 -> 5,144,320
  const size_t OFF_KEEPW  = 5144320;    // 752
  const size_t OFF_ROIBOX = 5145088;    // 32,000 -> 5,177,088
  const size_t OFF_PART   = 5816320;    // KS * 4MB split-K partials

  float* sharedb = (float*)(w + OFF_SHARED);
  float* cls     = (float*)(w + OFF_CLS);
  float* bbox    = (float*)(w + OFF_BBOX);
  float* scores  = (float*)(w + OFF_SCORES);
  float* prop    = (float*)(w + OFF_PROP);
  u64*   keys    = (u64*)(w + OFF_KEYS);
  float4* topbox = (float4*)(w + OFF_TOPBOX);
  u64*   maskT   = (u64*)(w + OFF_MASK);
  u64*   keepw   = (u64*)(w + OFF_KEEPW);
  float4* roibox = (float4*)(w + OFF_ROIBOX);
  float* out     = (float*)d_out;

  const size_t SLICE = (size_t)M_POS * NCH * 4;
  int KS = 1;
  if (ws_size >= OFF_PART + 8 * SLICE) KS = 8;
  else if (ws_size >= OFF_PART + 4 * SLICE) KS = 4;
  else if (ws_size >= OFF_PART + 2 * SLICE) KS = 2;
  float* part = (KS > 1) ? (float*)(w + OFF_PART) : sharedb;

  conv3x3<<<dim3(32, 2, KS), 256, 0, stream>>>(in, wsh, part, KTOT / KS);
  reduce_bias<<<4096, 256, 0, stream>>>(part, bsh, sharedb, KS);
  conv1x1<<<4096, 64, 0, stream>>>(sharedb, wcls, bcls, wbb, bbb, cls, bbox);
  proposals_k<<<144, 256, 0, stream>>>(cls, bbox, scores, prop);
  build_keys<<<256, 256, 0, stream>>>(scores, keys);
  sort_local<<<32, 1024, 0, stream>>>(keys);
  for (int k = 4096; k <= NSORT; k <<= 1) {
    int j = k >> 1;
    while (j >= 4096) {
      sort_gstep2<<<64, 256, 0, stream>>>(keys, k, j);
      j >>= 2;
    }
    if (j == 2048) {
      sort_gstep<<<128, 256, 0, stream>>>(keys, k, j);
      j >>= 1;
    }
    sort_lstep<<<32, 1024, 0, stream>>>(keys, k);
  }
  gather_top<<<24, 256, 0, stream>>>(keys, (const float4*)prop, topbox);
  nms_mask<<<dim3(NGRP, NGRP), 64, 0, stream>>>(topbox, maskT);
  nms_scan<<<1, 512, 0, stream>>>(maskT, keepw);
  select_rois<<<1, 1024, 0, stream>>>(keepw, topbox, roibox);
  roi_sample<<<1, 1024, 0, stream>>>(roibox, gt, out);
}